// Round 2
// baseline (442.662 us; speedup 1.0000x reference)
//
#include <hip/hip_runtime.h>

#define B_   32
#define T_   8192
#define F_   16
#define OUT_ 24
#define K1_  10
#define ND   19            // combined kernel width
#define NDP  20            // padded to 20 d-values (d=19 weights = 0)
#define KP   320           // padded K = NDP*16
#define JP   32            // padded N
#define XROWS 148          // staged x rows: t0-18 .. t0+129
#define XST  24            // xs row stride in shorts (48 B, 16B-aligned)
#define WST  328           // wt row stride in shorts (656 B = 41*16, 16B-aligned)

typedef short short8 __attribute__((ext_vector_type(8)));
typedef float float4v __attribute__((ext_vector_type(4)));

__device__ __forceinline__ unsigned short f2bf(float f) {
    unsigned u = __builtin_bit_cast(unsigned, f);
    unsigned r = (u + 0x7fffu + ((u >> 16) & 1u)) >> 16;  // RNE
    return (unsigned short)r;
}

// ---------------- precompute: W2 (bf16, padded [32][320]) + Bc[24] (fp32)
// grid = 32*20 blocks (j, d), 128 threads
__global__ void prep_kernel(const float* __restrict__ w1, const float* __restrict__ b1,
                            const float* __restrict__ wf, const float* __restrict__ bf,
                            unsigned short* __restrict__ w2bf, float* __restrict__ bcg) {
    int blk = blockIdx.x;
    int j = blk / NDP, d = blk % NDP;
    int c = threadIdx.x;
    __shared__ float red[16][128];
    __shared__ float red2[128];

    if (j < OUT_ && d < ND) {
        float p[16];
#pragma unroll
        for (int i = 0; i < 16; ++i) p[i] = 0.f;
        int klo = d - 9 > 0 ? d - 9 : 0;
        int khi = d < 9 ? d : 9;
        for (int k = klo; k <= khi; ++k) {
            float wfv = wf[j * 1280 + k * 128 + c];
            int k2 = d - k;
#pragma unroll
            for (int i = 0; i < 16; ++i)
                p[i] = fmaf(wfv, w1[(c * 16 + i) * 10 + k2], p[i]);
        }
#pragma unroll
        for (int i = 0; i < 16; ++i) red[i][c] = p[i];
        __syncthreads();
        for (int off = 64; off > 0; off >>= 1) {
            if (c < off) {
#pragma unroll
                for (int i = 0; i < 16; ++i) red[i][c] += red[i][c + off];
            }
            __syncthreads();
        }
        if (c < 16) w2bf[j * KP + d * 16 + c] = f2bf(red[c][0]);
    } else {
        if (c < 16) w2bf[j * KP + d * 16 + c] = 0;  // pad region
    }

    if (d == ND && j < OUT_) {   // d==19 blocks also compute Bc[j]
        float s = 0.f;
#pragma unroll
        for (int k = 0; k < K1_; ++k) s += wf[j * 1280 + k * 128 + c];
        s *= b1[c];
        red2[c] = s;
        __syncthreads();
        for (int off = 64; off > 0; off >>= 1) {
            if (c < off) red2[c] += red2[c + off];
            __syncthreads();
        }
        if (c == 0) bcg[j] = bf[j] + red2[0];
    }
}

// ---------------- main: MFMA GEMM, 128 timesteps per block, + head fixup in block x==0
__global__ __launch_bounds__(256) void main_kernel(const float* __restrict__ x,
                                                   const unsigned short* __restrict__ w2bf,
                                                   const float* __restrict__ bcg,
                                                   float* __restrict__ out,
                                                   const float* __restrict__ w1,
                                                   const float* __restrict__ b1,
                                                   const float* __restrict__ wf,
                                                   const float* __restrict__ bf) {
    __shared__ short xs[XROWS * XST];   // 7104 B : bf16 x rows [t0-18 .. t0+129]
    __shared__ short wt[JP * WST];      // 20992 B: bf16 W^T [j][k], stride 328

    int tid = threadIdx.x;
    int b = blockIdx.y;
    int t0 = blockIdx.x * 128;
    const float* xb = x + (long)b * T_ * F_;

    // stage W^T: global [32][320] tight -> LDS stride 328
    for (int idx = tid; idx < JP * 40; idx += 256) {       // 1280 chunks of 16B
        int j = idx / 40, s = idx % 40;
        uint4 v = *(const uint4*)(w2bf + j * KP + s * 8);
        *(uint4*)(wt + j * WST + s * 8) = v;
    }
    // stage x rows -> bf16
    for (int task = tid; task < XROWS * 2; task += 256) {
        int r = task >> 1, h = task & 1;
        int t = t0 - 18 + r;
        short8 v;
        if (t >= 0 && t < T_) {
            const float* p = xb + (long)t * 16 + h * 8;
            float4 f0 = *(const float4*)p;
            float4 f1 = *(const float4*)(p + 4);
            v[0] = (short)f2bf(f0.x); v[1] = (short)f2bf(f0.y);
            v[2] = (short)f2bf(f0.z); v[3] = (short)f2bf(f0.w);
            v[4] = (short)f2bf(f1.x); v[5] = (short)f2bf(f1.y);
            v[6] = (short)f2bf(f1.z); v[7] = (short)f2bf(f1.w);
        } else {
            v = short8{0, 0, 0, 0, 0, 0, 0, 0};
        }
        *(short8*)(xs + r * XST + h * 8) = v;
    }
    __syncthreads();

    int lane = tid & 63, w = tid >> 6;
    int m = lane & 15, quad = lane >> 4;
    int i0 = (quad & 1) * 8;        // short offset within xs row
    int dq = quad >> 1;             // d offset from quad
    int rbase0 = w * 32 + m + dq;   // mt = 0
    int rbase1 = rbase0 + 16;       // mt = 1
    int jb = m;                     // B-frag row (col of W)

    float4v acc[2][2];
#pragma unroll
    for (int mt = 0; mt < 2; ++mt)
#pragma unroll
        for (int nt = 0; nt < 2; ++nt) acc[mt][nt] = float4v{0.f, 0.f, 0.f, 0.f};

#pragma unroll
    for (int ks = 0; ks < 10; ++ks) {
        short8 a0 = *(const short8*)(xs + (rbase0 + 2 * ks) * XST + i0);
        short8 a1 = *(const short8*)(xs + (rbase1 + 2 * ks) * XST + i0);
        short8 b0 = *(const short8*)(wt + jb * WST + ks * 32 + quad * 8);
        short8 b1v = *(const short8*)(wt + (16 + jb) * WST + ks * 32 + quad * 8);
        acc[0][0] = __builtin_amdgcn_mfma_f32_16x16x32_bf16(a0, b0, acc[0][0], 0, 0, 0);
        acc[0][1] = __builtin_amdgcn_mfma_f32_16x16x32_bf16(a0, b1v, acc[0][1], 0, 0, 0);
        acc[1][0] = __builtin_amdgcn_mfma_f32_16x16x32_bf16(a1, b0, acc[1][0], 0, 0, 0);
        acc[1][1] = __builtin_amdgcn_mfma_f32_16x16x32_bf16(a1, b1v, acc[1][1], 0, 0, 0);
    }

    // epilogue: C[row][col], col = lane&15 (+nt*16), row = quad*4 + reg
    long outb = (long)b * T_;
    float bc0 = bcg[m];                          // j = m < 24 always
    float bc1 = (m < 8) ? bcg[16 + m] : 0.f;     // j = 16+m valid iff m < 8
#pragma unroll
    for (int mt = 0; mt < 2; ++mt) {
        int trow = t0 + w * 32 + mt * 16 + quad * 4;
#pragma unroll
        for (int reg = 0; reg < 4; ++reg) {
            int t = trow + reg;
            if (t >= 9) {   // t<9 written by head fixup below
                float* o = out + (outb + t) * OUT_;
                o[m] = acc[mt][0][reg] + bc0;
                if (m < 8) o[16 + m] = acc[mt][1][reg] + bc1;
            }
        }
    }

    // ------- head fixup (exact two-stage, replicate-clamp) for t in [0,9)
    if (blockIdx.x == 0) {
        __syncthreads();                 // everyone done reading xs
        float* hh = (float*)xs;          // 9*128 floats = 4608 B <= 7104 B
        for (int idx = tid; idx < 9 * 128; idx += 256) {
            int u = idx >> 7, c = idx & 127;
            float h = b1[c];
            for (int k = 9 - u; k <= 9; ++k) {
                int tau = u + k - 9;
#pragma unroll
                for (int i = 0; i < 16; ++i)
                    h = fmaf(xb[tau * 16 + i], w1[(c * 16 + i) * 10 + k], h);
            }
            hh[u * 128 + c] = h;
        }
        __syncthreads();
        if (tid < 9 * OUT_) {
            int t = tid / OUT_, j = tid % OUT_;
            float y = bf[j];
            for (int k = 0; k < K1_; ++k) {
                int u = t + k - 9;
                if (u < 0) u = 0;
                const float* wrow = wf + j * 1280 + k * 128;
                for (int c = 0; c < 128; ++c) y = fmaf(wrow[c], hh[u * 128 + c], y);
            }
            out[(outb + t) * OUT_ + j] = y;
        }
    }
}

extern "C" void kernel_launch(void* const* d_in, const int* in_sizes, int n_in,
                              void* d_out, int out_size, void* d_ws, size_t ws_size,
                              hipStream_t stream) {
    const float* x  = (const float*)d_in[0];
    const float* w1 = (const float*)d_in[1];
    const float* b1 = (const float*)d_in[2];
    const float* wf = (const float*)d_in[3];
    const float* bf = (const float*)d_in[4];
    float* out = (float*)d_out;
    unsigned short* w2bf = (unsigned short*)d_ws;                    // 32*320 bf16 = 20480 B
    float* bcg = (float*)((char*)d_ws + JP * KP * sizeof(unsigned short));  // 24 floats

    hipLaunchKernelGGL(prep_kernel, dim3(JP * NDP), dim3(128), 0, stream,
                       w1, b1, wf, bf, w2bf, bcg);
    hipLaunchKernelGGL(main_kernel, dim3(T_ / 128, B_), dim3(256), 0, stream,
                       x, w2bf, bcg, out, w1, b1, wf, bf);
}

// Round 3
// 129.935 us; speedup vs baseline: 3.4068x; 3.4068x over previous
//
#include <hip/hip_runtime.h>

#define B_   32
#define T_   8192
#define F_   16
#define OUT_ 24
#define K1_  10
#define ND   19            // combined kernel width
#define NDP  20            // padded d (d=19 weights = 0)
#define KP   320           // padded K = NDP*16
#define JP   32            // padded N
#define XROWS 148          // staged x rows: t0-18 .. t0+129
#define XST  24            // xs row stride in shorts (48 B)
#define WST  328           // wt row stride in shorts (656 B)

// ws layout (bytes): [0,20480) W2 bf16 [32][320]; [20480,20576) Bc fp32 [24];
//                    [20576, 20576+124416) E fp32 [9][24][9][16]
#define WS_BC_OFF  20480
#define WS_E_OFF   20576

typedef short short8 __attribute__((ext_vector_type(8)));
typedef float float4v __attribute__((ext_vector_type(4)));

__device__ __forceinline__ unsigned short f2bf(float f) {
    unsigned u = __builtin_bit_cast(unsigned, f);
    unsigned r = (u + 0x7fffu + ((u >> 16) & 1u)) >> 16;  // RNE
    return (unsigned short)r;
}

// ---------------- prep: W2 bf16 [32][320], Bc[24], E[9][24][9][16]
// grid = 640 (W2/Bc) + 1944 (E) blocks, 128 threads
__global__ void prep_kernel(const float* __restrict__ w1, const float* __restrict__ b1,
                            const float* __restrict__ wf, const float* __restrict__ bf,
                            unsigned short* __restrict__ w2bf, float* __restrict__ bcg,
                            float* __restrict__ Eg) {
    int blk = blockIdx.x;
    int c = threadIdx.x;
    __shared__ float red[16][128];
    __shared__ float red2[128];

    if (blk < JP * NDP) {
        int j = blk / NDP, d = blk % NDP;
        if (j < OUT_ && d < ND) {
            float p[16];
#pragma unroll
            for (int i = 0; i < 16; ++i) p[i] = 0.f;
            int klo = d - 9 > 0 ? d - 9 : 0;
            int khi = d < 9 ? d : 9;
            for (int k = klo; k <= khi; ++k) {
                float wfv = wf[j * 1280 + k * 128 + c];
                int k2 = d - k;
#pragma unroll
                for (int i = 0; i < 16; ++i)
                    p[i] = fmaf(wfv, w1[c * 160 + i * 10 + k2], p[i]);
            }
#pragma unroll
            for (int i = 0; i < 16; ++i) red[i][c] = p[i];
            __syncthreads();
            for (int off = 64; off > 0; off >>= 1) {
                if (c < off) {
#pragma unroll
                    for (int i = 0; i < 16; ++i) red[i][c] += red[i][c + off];
                }
                __syncthreads();
            }
            if (c < 16) w2bf[j * KP + d * 16 + c] = f2bf(red[c][0]);
        } else {
            if (c < 16) w2bf[j * KP + d * 16 + c] = 0;  // pad region
        }
        if (j < OUT_ && d == ND) {   // Bc[j]
            float s = 0.f;
#pragma unroll
            for (int k = 0; k < K1_; ++k) s += wf[j * 1280 + k * 128 + c];
            s *= b1[c];
            red2[c] = s;
            __syncthreads();
            for (int off = 64; off > 0; off >>= 1) {
                if (c < off) red2[c] += red2[c + off];
                __syncthreads();
            }
            if (c == 0) bcg[j] = bf[j] + red2[0];
        }
    } else {
        // E[t,j,tau,i] = sum_k wf[j,k,c] * w1[c,i, tau+9-u] * [tau <= u], u=max(t+k-9,0)
        int eidx = blk - JP * NDP;         // 0..1943
        int t = eidx / 216;
        int rem = eidx % 216;
        int j = rem / 9, tau = rem % 9;
        float p[16];
#pragma unroll
        for (int i = 0; i < 16; ++i) p[i] = 0.f;
        for (int k = 0; k < K1_; ++k) {
            int u = t + k - 9; if (u < 0) u = 0;
            if (tau > u) continue;
            int kap = tau + 9 - u;
            float wfv = wf[j * 1280 + k * 128 + c];
#pragma unroll
            for (int i = 0; i < 16; ++i)
                p[i] = fmaf(wfv, w1[c * 160 + i * 10 + kap], p[i]);
        }
#pragma unroll
        for (int i = 0; i < 16; ++i) red[i][c] = p[i];
        __syncthreads();
        for (int off = 64; off > 0; off >>= 1) {
            if (c < off) {
#pragma unroll
                for (int i = 0; i < 16; ++i) red[i][c] += red[i][c + off];
            }
            __syncthreads();
        }
        if (c < 16) Eg[((t * OUT_ + j) * 9 + tau) * 16 + c] = red[c][0];
    }
}

// ---------------- head: t in [0,9), y = Bc[j] + E[t,j,:,:] . x[b,0:9,:]
__global__ __launch_bounds__(256) void head_kernel(const float* __restrict__ x,
                                                   const float* __restrict__ Eg,
                                                   const float* __restrict__ bcg,
                                                   float* __restrict__ out) {
    int b = blockIdx.x, tid = threadIdx.x;
    if (tid >= 9 * OUT_) return;
    int t = tid / OUT_, j = tid % OUT_;
    const float4* xv = (const float4*)(x + (long)b * T_ * F_);   // first 36 vec4 used
    const float4* ev = (const float4*)(Eg + (long)tid * 144);
    float ax = 0.f, ay = 0.f, az = 0.f, aw = 0.f;
#pragma unroll
    for (int q = 0; q < 36; ++q) {
        float4 e = ev[q];
        float4 v = xv[q];
        ax = fmaf(e.x, v.x, ax);
        ay = fmaf(e.y, v.y, ay);
        az = fmaf(e.z, v.z, az);
        aw = fmaf(e.w, v.w, aw);
    }
    out[((long)b * T_ + t) * OUT_ + j] = bcg[j] + ((ax + ay) + (az + aw));
}

// ---------------- main: MFMA GEMM, 128 timesteps per block (t>=9 only)
__global__ __launch_bounds__(256) void main_kernel(const float* __restrict__ x,
                                                   const unsigned short* __restrict__ w2bf,
                                                   const float* __restrict__ bcg,
                                                   float* __restrict__ out) {
    __shared__ short xs[XROWS * XST];   // 7104 B : bf16 x rows [t0-18 .. t0+129]
    __shared__ short wt[JP * WST];      // 20992 B: bf16 W^T [j][k]

    int tid = threadIdx.x;
    int b = blockIdx.y;
    int t0 = blockIdx.x * 128;
    const float* xb = x + (long)b * T_ * F_;

    for (int idx = tid; idx < JP * 40; idx += 256) {       // stage W^T
        int j = idx / 40, s = idx % 40;
        uint4 v = *(const uint4*)(w2bf + j * KP + s * 8);
        *(uint4*)(wt + j * WST + s * 8) = v;
    }
    for (int task = tid; task < XROWS * 2; task += 256) {  // stage x -> bf16
        int r = task >> 1, h = task & 1;
        int t = t0 - 18 + r;
        short8 v;
        if (t >= 0 && t < T_) {
            const float* p = xb + (long)t * 16 + h * 8;
            float4 f0 = *(const float4*)p;
            float4 f1 = *(const float4*)(p + 4);
            v[0] = (short)f2bf(f0.x); v[1] = (short)f2bf(f0.y);
            v[2] = (short)f2bf(f0.z); v[3] = (short)f2bf(f0.w);
            v[4] = (short)f2bf(f1.x); v[5] = (short)f2bf(f1.y);
            v[6] = (short)f2bf(f1.z); v[7] = (short)f2bf(f1.w);
        } else {
            v = short8{0, 0, 0, 0, 0, 0, 0, 0};
        }
        *(short8*)(xs + r * XST + h * 8) = v;
    }
    __syncthreads();

    int lane = tid & 63, w = tid >> 6;
    int m = lane & 15, quad = lane >> 4;
    int i0 = (quad & 1) * 8;
    int dq = quad >> 1;
    int rbase0 = w * 32 + m + dq;
    int rbase1 = rbase0 + 16;
    int jb = m;

    float4v acc[2][2];
#pragma unroll
    for (int mt = 0; mt < 2; ++mt)
#pragma unroll
        for (int nt = 0; nt < 2; ++nt) acc[mt][nt] = float4v{0.f, 0.f, 0.f, 0.f};

#pragma unroll
    for (int ks = 0; ks < 10; ++ks) {
        short8 a0 = *(const short8*)(xs + (rbase0 + 2 * ks) * XST + i0);
        short8 a1 = *(const short8*)(xs + (rbase1 + 2 * ks) * XST + i0);
        short8 b0 = *(const short8*)(wt + jb * WST + ks * 32 + quad * 8);
        short8 b1v = *(const short8*)(wt + (16 + jb) * WST + ks * 32 + quad * 8);
        acc[0][0] = __builtin_amdgcn_mfma_f32_16x16x32_bf16(a0, b0, acc[0][0], 0, 0, 0);
        acc[0][1] = __builtin_amdgcn_mfma_f32_16x16x32_bf16(a0, b1v, acc[0][1], 0, 0, 0);
        acc[1][0] = __builtin_amdgcn_mfma_f32_16x16x32_bf16(a1, b0, acc[1][0], 0, 0, 0);
        acc[1][1] = __builtin_amdgcn_mfma_f32_16x16x32_bf16(a1, b1v, acc[1][1], 0, 0, 0);
    }

    long outb = (long)b * T_;
    float bc0 = bcg[m];
    float bc1 = (m < 8) ? bcg[16 + m] : 0.f;
#pragma unroll
    for (int mt = 0; mt < 2; ++mt) {
        int trow = t0 + w * 32 + mt * 16 + quad * 4;
#pragma unroll
        for (int reg = 0; reg < 4; ++reg) {
            int t = trow + reg;
            if (t >= 9) {   // t<9 written by head_kernel
                float* o = out + (outb + t) * OUT_;
                o[m] = acc[mt][0][reg] + bc0;
                if (m < 8) o[16 + m] = acc[mt][1][reg] + bc1;
            }
        }
    }
}

extern "C" void kernel_launch(void* const* d_in, const int* in_sizes, int n_in,
                              void* d_out, int out_size, void* d_ws, size_t ws_size,
                              hipStream_t stream) {
    const float* x  = (const float*)d_in[0];
    const float* w1 = (const float*)d_in[1];
    const float* b1 = (const float*)d_in[2];
    const float* wf = (const float*)d_in[3];
    const float* bf = (const float*)d_in[4];
    float* out = (float*)d_out;
    unsigned short* w2bf = (unsigned short*)d_ws;
    float* bcg = (float*)((char*)d_ws + WS_BC_OFF);
    float* Eg  = (float*)((char*)d_ws + WS_E_OFF);

    hipLaunchKernelGGL(prep_kernel, dim3(JP * NDP + 9 * OUT_ * 9), dim3(128), 0, stream,
                       w1, b1, wf, bf, w2bf, bcg, Eg);
    hipLaunchKernelGGL(main_kernel, dim3(T_ / 128, B_), dim3(256), 0, stream,
                       x, w2bf, bcg, out);
    hipLaunchKernelGGL(head_kernel, dim3(B_), dim3(256), 0, stream,
                       x, Eg, bcg, out);
}

// Round 5
// 123.356 us; speedup vs baseline: 3.5885x; 1.0533x over previous
//
#include <hip/hip_runtime.h>

#define B_   32
#define T_   8192
#define F_   16
#define OUT_ 24
#define K1_  10
#define ND   19            // combined kernel width
#define NDP  20            // padded d (d=19 weights = 0)
#define JP   32            // padded N

// ws layout (bytes):
// [0, 20480)            w2pk: bf16 packed B-frags  [tbl=2][ks=10][lane=64][z=8]
// [20480, 20576)        Bc fp32[24]
// [20576, 144992)       E fp32[9][24][9][16]
// [144992, 226912)      w1t fp32[(k*16+i)*128 + c]
#define WS_BC_OFF   20480
#define WS_E_OFF    20576
#define WS_W1T_OFF  144992

typedef short short8 __attribute__((ext_vector_type(8)));
typedef float float4v __attribute__((ext_vector_type(4)));

__device__ __forceinline__ unsigned short f2bf(float f) {
    unsigned u = __builtin_bit_cast(unsigned, f);
    unsigned r = (u + 0x7fffu + ((u >> 16) & 1u)) >> 16;  // RNE
    return (unsigned short)r;
}

// ---------------- w1 transpose: w1t[(k*16+i)*128+c] = w1[c*160+i*10+k]
__global__ void w1t_kernel(const float* __restrict__ w1, float* __restrict__ w1t) {
    int idx = blockIdx.x * 256 + threadIdx.x;   // 20480 total, grid 80
    float v = w1[idx];
    int c = idx / 160;
    int rem = idx - c * 160;
    int i = rem / 10;
    int k = rem - i * 10;
    w1t[(k * 16 + i) * 128 + c] = v;
}

// ---------------- prep: packed W2 bf16, Bc[24], E[9][24][9][16]
// grid = 640 (W2/Bc) + 1944 (E) blocks, 128 threads; all w1 reads via w1t (coalesced)
__global__ void prep_kernel(const float* __restrict__ w1t, const float* __restrict__ b1,
                            const float* __restrict__ wf, const float* __restrict__ bf,
                            unsigned short* __restrict__ w2pk, float* __restrict__ bcg,
                            float* __restrict__ Eg) {
    int blk = blockIdx.x;
    int c = threadIdx.x;
    __shared__ float red[16][128];
    __shared__ float red2[128];

    if (blk < JP * NDP) {
        int j = blk / NDP, d = blk % NDP;
        float p[16];
#pragma unroll
        for (int i = 0; i < 16; ++i) p[i] = 0.f;
        if (j < OUT_ && d < ND) {
            int klo = d - 9 > 0 ? d - 9 : 0;
            int khi = d < 9 ? d : 9;
            for (int k = klo; k <= khi; ++k) {
                float wfv = wf[j * 1280 + k * 128 + c];
                int k2 = d - k;
#pragma unroll
                for (int i = 0; i < 16; ++i)
                    p[i] = fmaf(wfv, w1t[(k2 * 16 + i) * 128 + c], p[i]);
            }
        }
#pragma unroll
        for (int i = 0; i < 16; ++i) red[i][c] = p[i];
        __syncthreads();
        for (int off = 64; off > 0; off >>= 1) {
            if (c < off) {
#pragma unroll
                for (int i = 0; i < 16; ++i) red[i][c] += red[i][c + off];
            }
            __syncthreads();
        }
        if (c < 16) {
            // packed B-frag write: value = W2[j][kk], kk = d*16+c
            int kk = d * 16 + c;
            int ks = kk >> 5, r = kk & 31;
            int quad = r >> 3, z = r & 7;
            int tbl = j >> 4, jj = j & 15;
            int lane = jj + quad * 16;
            w2pk[((tbl * 10 + ks) * 64 + lane) * 8 + z] = f2bf(red[c][0]);
        }
        if (j < OUT_ && d == ND) {   // Bc[j]
            float s = 0.f;
#pragma unroll
            for (int k = 0; k < K1_; ++k) s += wf[j * 1280 + k * 128 + c];
            s *= b1[c];
            red2[c] = s;
            __syncthreads();
            for (int off = 64; off > 0; off >>= 1) {
                if (c < off) red2[c] += red2[c + off];
                __syncthreads();
            }
            if (c == 0) bcg[j] = bf[j] + red2[0];
        }
    } else {
        // E[t,j,tau,i] = sum_k wf[j,k,c] * w1[c,i, tau+9-u] * [tau <= u], u=max(t+k-9,0)
        int eidx = blk - JP * NDP;         // 0..1943
        int t = eidx / 216;
        int rem = eidx % 216;
        int j = rem / 9, tau = rem % 9;
        float p[16];
#pragma unroll
        for (int i = 0; i < 16; ++i) p[i] = 0.f;
        for (int k = 0; k < K1_; ++k) {
            int u = t + k - 9; if (u < 0) u = 0;
            if (tau > u) continue;
            int kap = tau + 9 - u;
#pragma unroll
            for (int i = 0; i < 16; ++i)
                p[i] = fmaf(wf[j * 1280 + k * 128 + c], w1t[(kap * 16 + i) * 128 + c], p[i]);
        }
#pragma unroll
        for (int i = 0; i < 16; ++i) red[i][c] = p[i];
        __syncthreads();
        for (int off = 64; off > 0; off >>= 1) {
            if (c < off) {
#pragma unroll
                for (int i = 0; i < 16; ++i) red[i][c] += red[i][c + off];
            }
            __syncthreads();
        }
        if (c < 16) Eg[((t * OUT_ + j) * 9 + tau) * 16 + c] = red[c][0];
    }
}

// ---------------- head: t in [0,9), y = Bc[j] + E[t,j,:,:] . x[b,0:9,:]
__global__ __launch_bounds__(256) void head_kernel(const float* __restrict__ x,
                                                   const float* __restrict__ Eg,
                                                   const float* __restrict__ bcg,
                                                   float* __restrict__ out) {
    int b = blockIdx.x, tid = threadIdx.x;
    if (tid >= 9 * OUT_) return;
    int t = tid / OUT_, j = tid % OUT_;
    const float4* xv = (const float4*)(x + (long)b * T_ * F_);
    const float4* ev = (const float4*)(Eg + (long)tid * 144);
    float ax = 0.f, ay = 0.f, az = 0.f, aw = 0.f;
#pragma unroll
    for (int q = 0; q < 36; ++q) {
        float4 e = ev[q];
        float4 v = xv[q];
        ax = fmaf(e.x, v.x, ax);
        ay = fmaf(e.y, v.y, ay);
        az = fmaf(e.z, v.z, az);
        aw = fmaf(e.w, v.w, aw);
    }
    out[((long)b * T_ + t) * OUT_ + j] = bcg[j] + ((ax + ay) + (az + aw));
}

// ---------------- main: LDS-free MFMA GEMM
__device__ __forceinline__ short8 cvt8(float4 f0, float4 f1) {
    short8 v;
    v[0] = (short)f2bf(f0.x); v[1] = (short)f2bf(f0.y);
    v[2] = (short)f2bf(f0.z); v[3] = (short)f2bf(f0.w);
    v[4] = (short)f2bf(f1.x); v[5] = (short)f2bf(f1.y);
    v[6] = (short)f2bf(f1.z); v[7] = (short)f2bf(f1.w);
    return v;
}

template <bool GUARD>
__device__ __forceinline__ short8 load_a(const float* __restrict__ xb, int r, int halfsel) {
    int rc = r < T_ - 1 ? r : T_ - 1;   // d=19 pad column may index row T_: weights are 0, clamp
    if (GUARD) rc = rc > 0 ? rc : 0;
    const float4* p = (const float4*)(xb + (long)rc * 16 + halfsel);
    float4 f0 = p[0], f1 = p[1];
    short8 v = cvt8(f0, f1);
    if (GUARD && r < 0) v = short8{0, 0, 0, 0, 0, 0, 0, 0};
    return v;
}

template <bool GUARD>
__device__ __forceinline__ void kloop(const float* __restrict__ xb, int g0,
                                      const unsigned short* __restrict__ pk0,
                                      const unsigned short* __restrict__ pk1,
                                      int halfsel, float4v acc[2][2]) {
#pragma unroll
    for (int ks = 0; ks < 10; ++ks) {
        int r0 = g0 + 2 * ks;
        short8 a0 = load_a<GUARD>(xb, r0, halfsel);
        short8 a1 = load_a<GUARD>(xb, r0 + 16, halfsel);
        short8 b0 = *(const short8*)(pk0 + ks * 512);
        short8 b1 = *(const short8*)(pk1 + ks * 512);
        acc[0][0] = __builtin_amdgcn_mfma_f32_16x16x32_bf16(a0, b0, acc[0][0], 0, 0, 0);
        acc[0][1] = __builtin_amdgcn_mfma_f32_16x16x32_bf16(a0, b1, acc[0][1], 0, 0, 0);
        acc[1][0] = __builtin_amdgcn_mfma_f32_16x16x32_bf16(a1, b0, acc[1][0], 0, 0, 0);
        acc[1][1] = __builtin_amdgcn_mfma_f32_16x16x32_bf16(a1, b1, acc[1][1], 0, 0, 0);
    }
}

__global__ __launch_bounds__(256) void main_kernel(const float* __restrict__ x,
                                                   const unsigned short* __restrict__ w2pk,
                                                   const float* __restrict__ bcg,
                                                   float* __restrict__ out) {
    int tid = threadIdx.x;
    int lane = tid & 63, w = tid >> 6;
    int b = blockIdx.y;
    int t0 = blockIdx.x * 128;
    const float* xb = x + (long)b * T_ * F_;

    int m = lane & 15, quad = lane >> 4;
    int halfsel = (quad & 1) * 8;       // element offset within x row
    int dq = quad >> 1;
    int g0 = t0 - 18 + w * 32 + m + dq; // x row for mt=0, ks=0
    const unsigned short* pk0 = w2pk + lane * 8;           // tbl 0 (j = m)
    const unsigned short* pk1 = w2pk + 5120 + lane * 8;    // tbl 1 (j = 16+m)

    float4v acc[2][2];
#pragma unroll
    for (int mt = 0; mt < 2; ++mt)
#pragma unroll
        for (int nt = 0; nt < 2; ++nt) acc[mt][nt] = float4v{0.f, 0.f, 0.f, 0.f};

    if (blockIdx.x == 0 && w == 0)
        kloop<true>(xb, g0, pk0, pk1, halfsel, acc);
    else
        kloop<false>(xb, g0, pk0, pk1, halfsel, acc);

    long outb = (long)b * T_;
    float bc0 = bcg[m];
    float bc1 = (m < 8) ? bcg[16 + m] : 0.f;
#pragma unroll
    for (int mt = 0; mt < 2; ++mt) {
        int trow = t0 + w * 32 + mt * 16 + quad * 4;
#pragma unroll
        for (int reg = 0; reg < 4; ++reg) {
            int t = trow + reg;
            if (t >= 9) {   // t<9 written by head_kernel
                float* o = out + (outb + t) * OUT_;
                o[m] = acc[mt][0][reg] + bc0;
                if (m < 8) o[16 + m] = acc[mt][1][reg] + bc1;
            }
        }
    }
}

extern "C" void kernel_launch(void* const* d_in, const int* in_sizes, int n_in,
                              void* d_out, int out_size, void* d_ws, size_t ws_size,
                              hipStream_t stream) {
    const float* x  = (const float*)d_in[0];
    const float* w1 = (const float*)d_in[1];
    const float* b1 = (const float*)d_in[2];
    const float* wf = (const float*)d_in[3];
    const float* bf = (const float*)d_in[4];
    float* out = (float*)d_out;
    unsigned short* w2pk = (unsigned short*)d_ws;
    float* bcg = (float*)((char*)d_ws + WS_BC_OFF);
    float* Eg  = (float*)((char*)d_ws + WS_E_OFF);
    float* w1t = (float*)((char*)d_ws + WS_W1T_OFF);

    hipLaunchKernelGGL(w1t_kernel, dim3(80), dim3(256), 0, stream, w1, w1t);
    hipLaunchKernelGGL(prep_kernel, dim3(JP * NDP + 9 * OUT_ * 9), dim3(128), 0, stream,
                       w1t, b1, wf, bf, w2pk, bcg, Eg);
    hipLaunchKernelGGL(main_kernel, dim3(T_ / 128, B_), dim3(256), 0, stream,
                       x, w2pk, bcg, out);
    hipLaunchKernelGGL(head_kernel, dim3(B_), dim3(256), 0, stream,
                       x, Eg, bcg, out);
}

// Round 6
// 103.653 us; speedup vs baseline: 4.2706x; 1.1901x over previous
//
#include <hip/hip_runtime.h>

#define B_   32
#define T_   8192
#define F_   16
#define OUT_ 24
#define K1_  10
#define ND   19            // combined kernel width
#define NDP  20            // padded d (d=19 weights = 0)
#define JP   32            // padded N
#define PADL 24            // zeroed pad rows before t=0 in xbf
#define XROWS_TOT (PADL + T_ + 8)   // 8224 rows per batch

// ws layout (bytes):
// [0, 20480)            w2pk: bf16 packed B-frags  [tbl=2][ks=10][lane=64][z=8]
// [20480, 20576)        Bc fp32[24]
// [20576, 144992)       E fp32[9][24][9][16]
// [144992, 226912)      w1t fp32[(k*16+i)*128 + c]
// [226944, +8421376)    xbf bf16 [32][8224][16]  (zero-padded rows)
#define WS_BC_OFF   20480
#define WS_E_OFF    20576
#define WS_W1T_OFF  144992
#define WS_XBF_OFF  226944

typedef short short8 __attribute__((ext_vector_type(8)));
typedef float float4v __attribute__((ext_vector_type(4)));

__device__ __forceinline__ unsigned short f2bf(float f) {
    unsigned u = __builtin_bit_cast(unsigned, f);
    unsigned r = (u + 0x7fffu + ((u >> 16) & 1u)) >> 16;  // RNE
    return (unsigned short)r;
}

__device__ __forceinline__ short8 cvt8(float4 f0, float4 f1) {
    short8 v;
    v[0] = (short)f2bf(f0.x); v[1] = (short)f2bf(f0.y);
    v[2] = (short)f2bf(f0.z); v[3] = (short)f2bf(f0.w);
    v[4] = (short)f2bf(f1.x); v[5] = (short)f2bf(f1.y);
    v[6] = (short)f2bf(f1.z); v[7] = (short)f2bf(f1.w);
    return v;
}

// ---------------- w1 transpose: w1t[(k*16+i)*128+c] = w1[c*160+i*10+k]
__global__ void w1t_kernel(const float* __restrict__ w1, float* __restrict__ w1t) {
    int idx = blockIdx.x * 256 + threadIdx.x;   // 20480 total, grid 80
    float v = w1[idx];
    int c = idx / 160;
    int rem = idx - c * 160;
    int i = rem / 10;
    int k = rem - i * 10;
    w1t[(k * 16 + i) * 128 + c] = v;
}

// ---------------- xbf: padded bf16 copy of x. one thread per row (16 elems)
__global__ __launch_bounds__(256) void xbf_kernel(const float* __restrict__ x,
                                                  unsigned short* __restrict__ xbf) {
    int id = blockIdx.x * 256 + threadIdx.x;    // 32*8224 = 263168, grid 1028
    if (id >= B_ * XROWS_TOT) return;
    int b = id / XROWS_TOT, r = id - b * XROWS_TOT;
    unsigned short* dst = xbf + (size_t)id * 16;
    int t = r - PADL;
    short8 v0 = short8{0,0,0,0,0,0,0,0}, v1 = v0;
    if (t >= 0 && t < T_) {
        const float4* p = (const float4*)(x + ((long)b * T_ + t) * 16);
        float4 f0 = p[0], f1 = p[1], f2 = p[2], f3 = p[3];
        v0 = cvt8(f0, f1);
        v1 = cvt8(f2, f3);
    }
    *(short8*)dst = v0;
    *(short8*)(dst + 8) = v1;
}

// ---------------- prep: packed W2 bf16, Bc[24], E[9][24][9][16]
__global__ void prep_kernel(const float* __restrict__ w1t, const float* __restrict__ b1,
                            const float* __restrict__ wf, const float* __restrict__ bf,
                            unsigned short* __restrict__ w2pk, float* __restrict__ bcg,
                            float* __restrict__ Eg) {
    int blk = blockIdx.x;
    int c = threadIdx.x;
    __shared__ float red[16][128];
    __shared__ float red2[128];

    if (blk < JP * NDP) {
        int j = blk / NDP, d = blk % NDP;
        float p[16];
#pragma unroll
        for (int i = 0; i < 16; ++i) p[i] = 0.f;
        if (j < OUT_ && d < ND) {
            int klo = d - 9 > 0 ? d - 9 : 0;
            int khi = d < 9 ? d : 9;
            for (int k = klo; k <= khi; ++k) {
                float wfv = wf[j * 1280 + k * 128 + c];
                int k2 = d - k;
#pragma unroll
                for (int i = 0; i < 16; ++i)
                    p[i] = fmaf(wfv, w1t[(k2 * 16 + i) * 128 + c], p[i]);
            }
        }
#pragma unroll
        for (int i = 0; i < 16; ++i) red[i][c] = p[i];
        __syncthreads();
        for (int off = 64; off > 0; off >>= 1) {
            if (c < off) {
#pragma unroll
                for (int i = 0; i < 16; ++i) red[i][c] += red[i][c + off];
            }
            __syncthreads();
        }
        if (c < 16) {
            int kk = d * 16 + c;
            int ks = kk >> 5, r = kk & 31;
            int quad = r >> 3, z = r & 7;
            int tbl = j >> 4, jj = j & 15;
            int lane = jj + quad * 16;
            w2pk[((tbl * 10 + ks) * 64 + lane) * 8 + z] = f2bf(red[c][0]);
        }
        if (j < OUT_ && d == ND) {   // Bc[j]
            float s = 0.f;
#pragma unroll
            for (int k = 0; k < K1_; ++k) s += wf[j * 1280 + k * 128 + c];
            s *= b1[c];
            red2[c] = s;
            __syncthreads();
            for (int off = 64; off > 0; off >>= 1) {
                if (c < off) red2[c] += red2[c + off];
                __syncthreads();
            }
            if (c == 0) bcg[j] = bf[j] + red2[0];
        }
    } else {
        // E[t,j,tau,i] = sum_k wf[j,k,c] * w1[c,i, tau+9-u] * [tau <= u], u=max(t+k-9,0)
        int eidx = blk - JP * NDP;         // 0..1943
        int t = eidx / 216;
        int rem = eidx % 216;
        int j = rem / 9, tau = rem % 9;
        float p[16];
#pragma unroll
        for (int i = 0; i < 16; ++i) p[i] = 0.f;
        for (int k = 0; k < K1_; ++k) {
            int u = t + k - 9; if (u < 0) u = 0;
            if (tau > u) continue;
            int kap = tau + 9 - u;
#pragma unroll
            for (int i = 0; i < 16; ++i)
                p[i] = fmaf(wf[j * 1280 + k * 128 + c], w1t[(kap * 16 + i) * 128 + c], p[i]);
        }
#pragma unroll
        for (int i = 0; i < 16; ++i) red[i][c] = p[i];
        __syncthreads();
        for (int off = 64; off > 0; off >>= 1) {
            if (c < off) {
#pragma unroll
                for (int i = 0; i < 16; ++i) red[i][c] += red[i][c + off];
            }
            __syncthreads();
        }
        if (c < 16) Eg[((t * OUT_ + j) * 9 + tau) * 16 + c] = red[c][0];
    }
}

// ---------------- head: t in [0,9), y = Bc[j] + E[t,j,:,:] . x[b,0:9,:]
__global__ __launch_bounds__(256) void head_kernel(const float* __restrict__ x,
                                                   const float* __restrict__ Eg,
                                                   const float* __restrict__ bcg,
                                                   float* __restrict__ out) {
    int b = blockIdx.x, tid = threadIdx.x;
    if (tid >= 9 * OUT_) return;
    int t = tid / OUT_, j = tid % OUT_;
    const float4* xv = (const float4*)(x + (long)b * T_ * F_);
    const float4* ev = (const float4*)(Eg + (long)tid * 144);
    float ax = 0.f, ay = 0.f, az = 0.f, aw = 0.f;
#pragma unroll
    for (int q = 0; q < 36; ++q) {
        float4 e = ev[q];
        float4 v = xv[q];
        ax = fmaf(e.x, v.x, ax);
        ay = fmaf(e.y, v.y, ay);
        az = fmaf(e.z, v.z, az);
        aw = fmaf(e.w, v.w, aw);
    }
    out[((long)b * T_ + t) * OUT_ + j] = bcg[j] + ((ax + ay) + (az + aw));
}

// ---------------- main: LDS-free MFMA GEMM, K-outer / m-inner, all-bf16 loads
__global__ __launch_bounds__(256) void main_kernel(const unsigned short* __restrict__ xbf,
                                                   const unsigned short* __restrict__ w2pk,
                                                   const float* __restrict__ bcg,
                                                   float* __restrict__ out) {
    int tid = threadIdx.x;
    int lane = tid & 63, w = tid >> 6;
    int b = blockIdx.y;
    int t0 = blockIdx.x * 256;           // 256 timesteps per block, 64 per wave

    int m = lane & 15, quad = lane >> 4;
    int ih = (quad & 1) * 8;             // i-half within row
    int dq = quad >> 1;                  // d offset within K-step
    const unsigned short* xb = xbf + (size_t)b * XROWS_TOT * 16;
    int base = PADL + t0 + w * 64 + m + dq - 18;   // row for mt=0, ks=0
    const unsigned short* pk0 = w2pk + lane * 8;          // j = m
    const unsigned short* pk1 = w2pk + 5120 + lane * 8;   // j = 16+m

    float4v acc[4][2];
#pragma unroll
    for (int mt = 0; mt < 4; ++mt)
#pragma unroll
        for (int nt = 0; nt < 2; ++nt) acc[mt][nt] = float4v{0.f, 0.f, 0.f, 0.f};

#pragma unroll
    for (int ks = 0; ks < 10; ++ks) {
        short8 b0 = *(const short8*)(pk0 + ks * 512);
        short8 b1 = *(const short8*)(pk1 + ks * 512);
#pragma unroll
        for (int mt = 0; mt < 4; ++mt) {
            short8 a = *(const short8*)(xb + (size_t)(base + mt * 16 + 2 * ks) * 16 + ih);
            acc[mt][0] = __builtin_amdgcn_mfma_f32_16x16x32_bf16(a, b0, acc[mt][0], 0, 0, 0);
            acc[mt][1] = __builtin_amdgcn_mfma_f32_16x16x32_bf16(a, b1, acc[mt][1], 0, 0, 0);
        }
    }

    // epilogue: C col = lane&15 (j), row = quad*4+reg (t offset); t<9 overwritten by head later
    long outb = (long)b * T_;
    float bc0 = bcg[m];
    float bc1 = (m < 8) ? bcg[16 + m] : 0.f;
#pragma unroll
    for (int mt = 0; mt < 4; ++mt) {
        int trow = t0 + w * 64 + mt * 16 + quad * 4;
#pragma unroll
        for (int reg = 0; reg < 4; ++reg) {
            int t = trow + reg;
            float* o = out + (outb + t) * OUT_;
            o[m] = acc[mt][0][reg] + bc0;
            if (m < 8) o[16 + m] = acc[mt][1][reg] + bc1;
        }
    }
}

extern "C" void kernel_launch(void* const* d_in, const int* in_sizes, int n_in,
                              void* d_out, int out_size, void* d_ws, size_t ws_size,
                              hipStream_t stream) {
    const float* x  = (const float*)d_in[0];
    const float* w1 = (const float*)d_in[1];
    const float* b1 = (const float*)d_in[2];
    const float* wf = (const float*)d_in[3];
    const float* bf = (const float*)d_in[4];
    float* out = (float*)d_out;
    unsigned short* w2pk = (unsigned short*)d_ws;
    float* bcg = (float*)((char*)d_ws + WS_BC_OFF);
    float* Eg  = (float*)((char*)d_ws + WS_E_OFF);
    float* w1t = (float*)((char*)d_ws + WS_W1T_OFF);
    unsigned short* xbf = (unsigned short*)((char*)d_ws + WS_XBF_OFF);

    hipLaunchKernelGGL(w1t_kernel, dim3(80), dim3(256), 0, stream, w1, w1t);
    hipLaunchKernelGGL(xbf_kernel, dim3((B_ * XROWS_TOT + 255) / 256), dim3(256), 0, stream,
                       x, xbf);
    hipLaunchKernelGGL(prep_kernel, dim3(JP * NDP + 9 * OUT_ * 9), dim3(128), 0, stream,
                       w1t, b1, wf, bf, w2pk, bcg, Eg);
    hipLaunchKernelGGL(main_kernel, dim3(T_ / 256, B_), dim3(256), 0, stream,
                       xbf, w2pk, bcg, out);
    hipLaunchKernelGGL(head_kernel, dim3(B_), dim3(256), 0, stream,
                       x, Eg, bcg, out);
}

// Round 7
// 102.730 us; speedup vs baseline: 4.3090x; 1.0090x over previous
//
#include <hip/hip_runtime.h>

#define B_   32
#define T_   8192
#define F_   16
#define OUT_ 24
#define K1_  10
#define ND   19            // combined kernel width
#define JP   32            // padded N
#define PADL 24            // zeroed pad rows before t=0 in xbf
#define XROWS_TOT (PADL + T_ + 8)   // 8224 rows per batch

// ws layout (bytes):
// [0, 20480)            w2pk: bf16 packed B-frags  [tbl=2][ks=10][lane=64][z=8]
// [20480, 20576)        Bc fp32[24]
// [20576, 144992)       E fp32[9][24][9][16]
// [144992, 226912)      w1t fp32[(k*16+i)*128 + c]
// [226944, +8421376)    xbf bf16 [32][8224][16]  (zero-padded rows)
#define WS_BC_OFF   20480
#define WS_E_OFF    20576
#define WS_W1T_OFF  144992
#define WS_XBF_OFF  226944

typedef short short8 __attribute__((ext_vector_type(8)));
typedef float float4v __attribute__((ext_vector_type(4)));

__device__ __forceinline__ unsigned short f2bf(float f) {
    unsigned u = __builtin_bit_cast(unsigned, f);
    unsigned r = (u + 0x7fffu + ((u >> 16) & 1u)) >> 16;  // RNE
    return (unsigned short)r;
}

__device__ __forceinline__ short8 cvt8(float4 f0, float4 f1) {
    short8 v;
    v[0] = (short)f2bf(f0.x); v[1] = (short)f2bf(f0.y);
    v[2] = (short)f2bf(f0.z); v[3] = (short)f2bf(f0.w);
    v[4] = (short)f2bf(f1.x); v[5] = (short)f2bf(f1.y);
    v[6] = (short)f2bf(f1.z); v[7] = (short)f2bf(f1.w);
    return v;
}

// ---------------- pre: xbf (blocks 0..1027) + w1t (1028..1107) + w2pk zero (1108..1147)
__global__ __launch_bounds__(256) void pre_kernel(const float* __restrict__ x,
                                                  const float* __restrict__ w1,
                                                  unsigned short* __restrict__ xbf,
                                                  float* __restrict__ w1t,
                                                  unsigned short* __restrict__ w2pk) {
    int bx = blockIdx.x;
    int tid = threadIdx.x;
    if (bx < 1028) {
        int id = bx * 256 + tid;                 // one row (16 elems) per thread
        if (id >= B_ * XROWS_TOT) return;
        int b = id / XROWS_TOT, r = id - b * XROWS_TOT;
        unsigned short* dst = xbf + (size_t)id * 16;
        int t = r - PADL;
        short8 v0 = short8{0,0,0,0,0,0,0,0}, v1 = v0;
        if (t >= 0 && t < T_) {
            const float4* p = (const float4*)(x + ((long)b * T_ + t) * 16);
            float4 f0 = p[0], f1 = p[1], f2 = p[2], f3 = p[3];
            v0 = cvt8(f0, f1);
            v1 = cvt8(f2, f3);
        }
        *(short8*)dst = v0;
        *(short8*)(dst + 8) = v1;
    } else if (bx < 1108) {
        int idx = (bx - 1028) * 256 + tid;       // 20480 elems
        float v = w1[idx];
        int c = idx / 160;
        int rem = idx - c * 160;
        int i = rem / 10;
        int k = rem - i * 10;
        w1t[(k * 16 + i) * 128 + c] = v;
    } else {
        int idx = (bx - 1108) * 256 + tid;       // 10240 uints = 20480 shorts
        ((unsigned*)w2pk)[idx] = 0;
    }
}

// ---------------- prep: wave-per-task, no barriers.
// waves 0..455: W2(j,d); 456..479: Bc(j); 480..2423: E(t,j,tau). grid 606 x 256.
__global__ __launch_bounds__(256) void prep_kernel(const float* __restrict__ w1t,
                                                   const float* __restrict__ b1,
                                                   const float* __restrict__ wf,
                                                   const float* __restrict__ bf,
                                                   unsigned short* __restrict__ w2pk,
                                                   float* __restrict__ bcg,
                                                   float* __restrict__ Eg) {
    int tid = threadIdx.x;
    int lane = tid & 63;
    int wid = blockIdx.x * 4 + (tid >> 6);

    if (wid < 456) {
        int j = wid / ND, d = wid % ND;
        float p[16];
#pragma unroll
        for (int i = 0; i < 16; ++i) p[i] = 0.f;
        int klo = d - 9 > 0 ? d - 9 : 0;
        int khi = d < 9 ? d : 9;
        for (int k = klo; k <= khi; ++k) {
            float w0 = wf[j * 1280 + k * 128 + lane];
            float w1v = wf[j * 1280 + k * 128 + 64 + lane];
            const float* wb = w1t + (d - k) * 16 * 128;
#pragma unroll
            for (int i = 0; i < 16; ++i)
                p[i] = fmaf(w0, wb[i * 128 + lane], fmaf(w1v, wb[i * 128 + 64 + lane], p[i]));
        }
#pragma unroll
        for (int i = 0; i < 16; ++i) {
            p[i] += __shfl_xor(p[i], 1);
            p[i] += __shfl_xor(p[i], 2);
            p[i] += __shfl_xor(p[i], 4);
            p[i] += __shfl_xor(p[i], 8);
            p[i] += __shfl_xor(p[i], 16);
            p[i] += __shfl_xor(p[i], 32);
        }
        if (lane < 16) {
            float v = p[0];
#pragma unroll
            for (int i = 1; i < 16; ++i)
                if (lane == i) v = p[i];
            int kk = d * 16 + lane;
            int ks = kk >> 5, r = kk & 31;
            int quad = r >> 3, z = r & 7;
            int tbl = j >> 4, jj = j & 15;
            int lt = jj + quad * 16;
            w2pk[((tbl * 10 + ks) * 64 + lt) * 8 + z] = f2bf(v);
        }
    } else if (wid < 480) {
        int j = wid - 456;
        float s0 = 0.f, s1 = 0.f;
#pragma unroll
        for (int k = 0; k < K1_; ++k) {
            s0 += wf[j * 1280 + k * 128 + lane];
            s1 += wf[j * 1280 + k * 128 + 64 + lane];
        }
        float s = s0 * b1[lane] + s1 * b1[64 + lane];
        s += __shfl_xor(s, 1);
        s += __shfl_xor(s, 2);
        s += __shfl_xor(s, 4);
        s += __shfl_xor(s, 8);
        s += __shfl_xor(s, 16);
        s += __shfl_xor(s, 32);
        if (lane == 0) bcg[j] = bf[j] + s;
    } else {
        // E[t,j,tau,i] = sum_k wf[j,k,c]*w1[c,i,tau+9-u]*[tau<=u], u=max(t+k-9,0)
        int eidx = wid - 480;                 // 0..1943
        int t = eidx / 216;
        int rem = eidx % 216;
        int j = rem / 9, tau = rem % 9;
        float p[16];
#pragma unroll
        for (int i = 0; i < 16; ++i) p[i] = 0.f;
        for (int k = 0; k < K1_; ++k) {
            int u = t + k - 9; if (u < 0) u = 0;
            if (tau > u) continue;
            int kap = tau + 9 - u;
            float w0 = wf[j * 1280 + k * 128 + lane];
            float w1v = wf[j * 1280 + k * 128 + 64 + lane];
            const float* wb = w1t + kap * 16 * 128;
#pragma unroll
            for (int i = 0; i < 16; ++i)
                p[i] = fmaf(w0, wb[i * 128 + lane], fmaf(w1v, wb[i * 128 + 64 + lane], p[i]));
        }
#pragma unroll
        for (int i = 0; i < 16; ++i) {
            p[i] += __shfl_xor(p[i], 1);
            p[i] += __shfl_xor(p[i], 2);
            p[i] += __shfl_xor(p[i], 4);
            p[i] += __shfl_xor(p[i], 8);
            p[i] += __shfl_xor(p[i], 16);
            p[i] += __shfl_xor(p[i], 32);
        }
        if (lane < 16) {
            float v = p[0];
#pragma unroll
            for (int i = 1; i < 16; ++i)
                if (lane == i) v = p[i];
            Eg[((t * OUT_ + j) * 9 + tau) * 16 + lane] = v;
        }
    }
}

// ---------------- main: LDS-free MFMA GEMM (blocks x=0..31) + head (block x=32)
__global__ __launch_bounds__(256) void main_kernel(const unsigned short* __restrict__ xbf,
                                                   const unsigned short* __restrict__ w2pk,
                                                   const float* __restrict__ bcg,
                                                   float* __restrict__ out,
                                                   const float* __restrict__ x,
                                                   const float* __restrict__ Eg) {
    int tid = threadIdx.x;
    int b = blockIdx.y;

    if (blockIdx.x == 32) {    // head: t in [0,9), y = Bc[j] + E[t,j,:,:] . x[b,0:9,:]
        if (tid >= 9 * OUT_) return;
        int t = tid / OUT_, j = tid % OUT_;
        const float4* xv = (const float4*)(x + (long)b * T_ * F_);
        const float4* ev = (const float4*)(Eg + (long)tid * 144);
        float ax = 0.f, ay = 0.f, az = 0.f, aw = 0.f;
#pragma unroll
        for (int q = 0; q < 36; ++q) {
            float4 e = ev[q];
            float4 v = xv[q];
            ax = fmaf(e.x, v.x, ax);
            ay = fmaf(e.y, v.y, ay);
            az = fmaf(e.z, v.z, az);
            aw = fmaf(e.w, v.w, aw);
        }
        out[((long)b * T_ + t) * OUT_ + j] = bcg[j] + ((ax + ay) + (az + aw));
        return;
    }

    int lane = tid & 63, w = tid >> 6;
    int t0 = blockIdx.x * 256;           // 256 timesteps per block, 64 per wave

    int m = lane & 15, quad = lane >> 4;
    int ih = (quad & 1) * 8;             // i-half within row
    int dq = quad >> 1;                  // d offset within K-step
    const unsigned short* xb = xbf + (size_t)b * XROWS_TOT * 16;
    int base = PADL + t0 + w * 64 + m + dq - 18;   // row for mt=0, ks=0
    const unsigned short* pk0 = w2pk + lane * 8;          // j = m
    const unsigned short* pk1 = w2pk + 5120 + lane * 8;   // j = 16+m

    // hoist all B-fragments into registers (read once per wave)
    short8 B0[10], B1[10];
#pragma unroll
    for (int ks = 0; ks < 10; ++ks) {
        B0[ks] = *(const short8*)(pk0 + ks * 512);
        B1[ks] = *(const short8*)(pk1 + ks * 512);
    }

    float4v acc[4][2];
#pragma unroll
    for (int mt = 0; mt < 4; ++mt)
#pragma unroll
        for (int nt = 0; nt < 2; ++nt) acc[mt][nt] = float4v{0.f, 0.f, 0.f, 0.f};

#pragma unroll
    for (int ks = 0; ks < 10; ++ks) {
#pragma unroll
        for (int mt = 0; mt < 4; ++mt) {
            short8 a = *(const short8*)(xb + (size_t)(base + mt * 16 + 2 * ks) * 16 + ih);
            acc[mt][0] = __builtin_amdgcn_mfma_f32_16x16x32_bf16(a, B0[ks], acc[mt][0], 0, 0, 0);
            acc[mt][1] = __builtin_amdgcn_mfma_f32_16x16x32_bf16(a, B1[ks], acc[mt][1], 0, 0, 0);
        }
    }

    // epilogue: C col = lane&15 (j), row = quad*4+reg; block 0 skips t<9 (head owns them)
    long outb = (long)b * T_;
    float bc0 = bcg[m];
    float bc1 = (m < 8) ? bcg[16 + m] : 0.f;
    bool edge = (blockIdx.x == 0);
#pragma unroll
    for (int mt = 0; mt < 4; ++mt) {
        int trow = t0 + w * 64 + mt * 16 + quad * 4;
#pragma unroll
        for (int reg = 0; reg < 4; ++reg) {
            int t = trow + reg;
            if (!edge || t >= 9) {
                float* o = out + (outb + t) * OUT_;
                o[m] = acc[mt][0][reg] + bc0;
                if (m < 8) o[16 + m] = acc[mt][1][reg] + bc1;
            }
        }
    }
}

extern "C" void kernel_launch(void* const* d_in, const int* in_sizes, int n_in,
                              void* d_out, int out_size, void* d_ws, size_t ws_size,
                              hipStream_t stream) {
    const float* x  = (const float*)d_in[0];
    const float* w1 = (const float*)d_in[1];
    const float* b1 = (const float*)d_in[2];
    const float* wf = (const float*)d_in[3];
    const float* bf = (const float*)d_in[4];
    float* out = (float*)d_out;
    unsigned short* w2pk = (unsigned short*)d_ws;
    float* bcg = (float*)((char*)d_ws + WS_BC_OFF);
    float* Eg  = (float*)((char*)d_ws + WS_E_OFF);
    float* w1t = (float*)((char*)d_ws + WS_W1T_OFF);
    unsigned short* xbf = (unsigned short*)((char*)d_ws + WS_XBF_OFF);

    hipLaunchKernelGGL(pre_kernel, dim3(1148), dim3(256), 0, stream,
                       x, w1, xbf, w1t, w2pk);
    hipLaunchKernelGGL(prep_kernel, dim3(606), dim3(256), 0, stream,
                       w1t, b1, wf, bf, w2pk, bcg, Eg);
    hipLaunchKernelGGL(main_kernel, dim3(33, B_), dim3(256), 0, stream,
                       xbf, w2pk, bcg, out, x, Eg);
}

// Round 8
// 102.246 us; speedup vs baseline: 4.3294x; 1.0047x over previous
//
#include <hip/hip_runtime.h>

#define B_   32
#define T_   8192
#define F_   16
#define OUT_ 24
#define K1_  10
#define ND   19            // combined kernel width
#define JP   32            // padded N
#define PADL 24            // zeroed pad rows before t=0 in xbf
#define XROWS_TOT (PADL + T_ + 8)   // 8224 rows per batch

// ws layout (bytes):
// [0, 20480)            w2pk: bf16 packed B-frags  [tbl=2][ks=10][lane=64][z=8]
// [20480, 20576)        Bc fp32[24]
// [20576, 144992)       E fp32[9][24][9][16]
// [144992, 226912)      w1t fp32[(k*16+i)*128 + c]
// [226944, +8421376)    xbf bf16 [32][8224][16]  (zero-padded rows)
#define WS_BC_OFF   20480
#define WS_E_OFF    20576
#define WS_W1T_OFF  144992
#define WS_XBF_OFF  226944

typedef short short8 __attribute__((ext_vector_type(8)));
typedef float float4v __attribute__((ext_vector_type(4)));

__device__ __forceinline__ unsigned short f2bf(float f) {
    unsigned u = __builtin_bit_cast(unsigned, f);
    unsigned r = (u + 0x7fffu + ((u >> 16) & 1u)) >> 16;  // RNE
    return (unsigned short)r;
}

__device__ __forceinline__ short8 cvt8(float4 f0, float4 f1) {
    short8 v;
    v[0] = (short)f2bf(f0.x); v[1] = (short)f2bf(f0.y);
    v[2] = (short)f2bf(f0.z); v[3] = (short)f2bf(f0.w);
    v[4] = (short)f2bf(f1.x); v[5] = (short)f2bf(f1.y);
    v[6] = (short)f2bf(f1.z); v[7] = (short)f2bf(f1.w);
    return v;
}

// ---------------- pre: xbf (blocks 0..1027) + w1t (1028..1107) + w2pk zero (1108..1147)
__global__ __launch_bounds__(256) void pre_kernel(const float* __restrict__ x,
                                                  const float* __restrict__ w1,
                                                  unsigned short* __restrict__ xbf,
                                                  float* __restrict__ w1t,
                                                  unsigned short* __restrict__ w2pk) {
    int bx = blockIdx.x;
    int tid = threadIdx.x;
    if (bx < 1028) {
        int id = bx * 256 + tid;                 // one row (16 elems) per thread
        if (id >= B_ * XROWS_TOT) return;
        int b = id / XROWS_TOT, r = id - b * XROWS_TOT;
        unsigned short* dst = xbf + (size_t)id * 16;
        int t = r - PADL;
        short8 v0 = short8{0,0,0,0,0,0,0,0}, v1 = v0;
        if (t >= 0 && t < T_) {
            const float4* p = (const float4*)(x + ((long)b * T_ + t) * 16);
            float4 f0 = p[0], f1 = p[1], f2 = p[2], f3 = p[3];
            v0 = cvt8(f0, f1);
            v1 = cvt8(f2, f3);
        }
        *(short8*)dst = v0;
        *(short8*)(dst + 8) = v1;
    } else if (bx < 1108) {
        int idx = (bx - 1028) * 256 + tid;       // 20480 elems
        float v = w1[idx];
        int c = idx / 160;
        int rem = idx - c * 160;
        int i = rem / 10;
        int k = rem - i * 10;
        w1t[(k * 16 + i) * 128 + c] = v;
    } else {
        int idx = (bx - 1108) * 256 + tid;       // 10240 uints = 20480 shorts
        ((unsigned*)w2pk)[idx] = 0;
    }
}

// ---------------- prep: wave-per-task, no barriers.
// waves 0..455: W2(j,d); 456..479: Bc(j); 480..2423: E(t,j,tau). grid 606 x 256.
__global__ __launch_bounds__(256) void prep_kernel(const float* __restrict__ w1t,
                                                   const float* __restrict__ b1,
                                                   const float* __restrict__ wf,
                                                   const float* __restrict__ bf,
                                                   unsigned short* __restrict__ w2pk,
                                                   float* __restrict__ bcg,
                                                   float* __restrict__ Eg) {
    int tid = threadIdx.x;
    int lane = tid & 63;
    int wid = blockIdx.x * 4 + (tid >> 6);

    if (wid < 456) {
        int j = wid / ND, d = wid % ND;
        float p[16];
#pragma unroll
        for (int i = 0; i < 16; ++i) p[i] = 0.f;
        int klo = d - 9 > 0 ? d - 9 : 0;
        int khi = d < 9 ? d : 9;
        for (int k = klo; k <= khi; ++k) {
            float w0 = wf[j * 1280 + k * 128 + lane];
            float w1v = wf[j * 1280 + k * 128 + 64 + lane];
            const float* wb = w1t + (d - k) * 16 * 128;
#pragma unroll
            for (int i = 0; i < 16; ++i)
                p[i] = fmaf(w0, wb[i * 128 + lane], fmaf(w1v, wb[i * 128 + 64 + lane], p[i]));
        }
#pragma unroll
        for (int i = 0; i < 16; ++i) {
            p[i] += __shfl_xor(p[i], 1);
            p[i] += __shfl_xor(p[i], 2);
            p[i] += __shfl_xor(p[i], 4);
            p[i] += __shfl_xor(p[i], 8);
            p[i] += __shfl_xor(p[i], 16);
            p[i] += __shfl_xor(p[i], 32);
        }
        if (lane < 16) {
            float v = p[0];
#pragma unroll
            for (int i = 1; i < 16; ++i)
                if (lane == i) v = p[i];
            int kk = d * 16 + lane;
            int ks = kk >> 5, r = kk & 31;
            int quad = r >> 3, z = r & 7;
            int tbl = j >> 4, jj = j & 15;
            int lt = jj + quad * 16;
            w2pk[((tbl * 10 + ks) * 64 + lt) * 8 + z] = f2bf(v);
        }
    } else if (wid < 480) {
        int j = wid - 456;
        float s0 = 0.f, s1 = 0.f;
#pragma unroll
        for (int k = 0; k < K1_; ++k) {
            s0 += wf[j * 1280 + k * 128 + lane];
            s1 += wf[j * 1280 + k * 128 + 64 + lane];
        }
        float s = s0 * b1[lane] + s1 * b1[64 + lane];
        s += __shfl_xor(s, 1);
        s += __shfl_xor(s, 2);
        s += __shfl_xor(s, 4);
        s += __shfl_xor(s, 8);
        s += __shfl_xor(s, 16);
        s += __shfl_xor(s, 32);
        if (lane == 0) bcg[j] = bf[j] + s;
    } else {
        // E[t,j,tau,i] = sum_k wf[j,k,c]*w1[c,i,tau+9-u]*[tau<=u], u=max(t+k-9,0)
        int eidx = wid - 480;                 // 0..1943
        int t = eidx / 216;
        int rem = eidx % 216;
        int j = rem / 9, tau = rem % 9;
        float p[16];
#pragma unroll
        for (int i = 0; i < 16; ++i) p[i] = 0.f;
        for (int k = 0; k < K1_; ++k) {
            int u = t + k - 9; if (u < 0) u = 0;
            if (tau > u) continue;
            int kap = tau + 9 - u;
            float w0 = wf[j * 1280 + k * 128 + lane];
            float w1v = wf[j * 1280 + k * 128 + 64 + lane];
            const float* wb = w1t + kap * 16 * 128;
#pragma unroll
            for (int i = 0; i < 16; ++i)
                p[i] = fmaf(w0, wb[i * 128 + lane], fmaf(w1v, wb[i * 128 + 64 + lane], p[i]));
        }
#pragma unroll
        for (int i = 0; i < 16; ++i) {
            p[i] += __shfl_xor(p[i], 1);
            p[i] += __shfl_xor(p[i], 2);
            p[i] += __shfl_xor(p[i], 4);
            p[i] += __shfl_xor(p[i], 8);
            p[i] += __shfl_xor(p[i], 16);
            p[i] += __shfl_xor(p[i], 32);
        }
        if (lane < 16) {
            float v = p[0];
#pragma unroll
            for (int i = 1; i < 16; ++i)
                if (lane == i) v = p[i];
            Eg[((t * OUT_ + j) * 9 + tau) * 16 + lane] = v;
        }
    }
}

// ---------------- main: LDS-free MFMA GEMM (blocks x=0..31) + head (block x=32)
// __launch_bounds__(256, 2): min 2 waves/EU -> VGPR budget 256, enough to keep
// all B-frags resident AND hoist A-loads (the R5-R7 kernels were register-starved
// at VGPR<=128 -> serialized load->MFMA chains, main ~23us).
__global__ __launch_bounds__(256, 2) void main_kernel(const unsigned short* __restrict__ xbf,
                                                      const unsigned short* __restrict__ w2pk,
                                                      const float* __restrict__ bcg,
                                                      float* __restrict__ out,
                                                      const float* __restrict__ x,
                                                      const float* __restrict__ Eg) {
    int tid = threadIdx.x;
    int b = blockIdx.y;

    if (blockIdx.x == 32) {    // head: t in [0,9), y = Bc[j] + E[t,j,:,:] . x[b,0:9,:]
        if (tid >= 9 * OUT_) return;
        int t = tid / OUT_, j = tid % OUT_;
        const float4* xv = (const float4*)(x + (long)b * T_ * F_);
        const float4* ev = (const float4*)(Eg + (long)tid * 144);
        float ax = 0.f, ay = 0.f, az = 0.f, aw = 0.f;
#pragma unroll
        for (int q = 0; q < 36; ++q) {
            float4 e = ev[q];
            float4 v = xv[q];
            ax = fmaf(e.x, v.x, ax);
            ay = fmaf(e.y, v.y, ay);
            az = fmaf(e.z, v.z, az);
            aw = fmaf(e.w, v.w, aw);
        }
        out[((long)b * T_ + t) * OUT_ + j] = bcg[j] + ((ax + ay) + (az + aw));
        return;
    }

    int lane = tid & 63, w = tid >> 6;
    int t0 = blockIdx.x * 256;           // 256 timesteps per block, 64 per wave

    int m = lane & 15, quad = lane >> 4;
    int ih = (quad & 1) * 8;             // i-half within row
    int dq = quad >> 1;                  // d offset within K-step
    const unsigned short* xb = xbf + (size_t)b * XROWS_TOT * 16;
    int base = PADL + t0 + w * 64 + m + dq - 18;   // row for mt=0, ks=0
    const unsigned short* pk0 = w2pk + lane * 8;          // j = m
    const unsigned short* pk1 = w2pk + 5120 + lane * 8;   // j = 16+m

    // hoist all B-fragments into registers (read once per wave)
    short8 B0[10], B1[10];
#pragma unroll
    for (int ks = 0; ks < 10; ++ks) {
        B0[ks] = *(const short8*)(pk0 + ks * 512);
        B1[ks] = *(const short8*)(pk1 + ks * 512);
    }

    float4v acc[4][2];
#pragma unroll
    for (int mt = 0; mt < 4; ++mt)
#pragma unroll
        for (int nt = 0; nt < 2; ++nt) acc[mt][nt] = float4v{0.f, 0.f, 0.f, 0.f};

#pragma unroll
    for (int ks = 0; ks < 10; ++ks) {
        short8 a0 = *(const short8*)(xb + (size_t)(base + 0 * 16 + 2 * ks) * 16 + ih);
        short8 a1 = *(const short8*)(xb + (size_t)(base + 1 * 16 + 2 * ks) * 16 + ih);
        short8 a2 = *(const short8*)(xb + (size_t)(base + 2 * 16 + 2 * ks) * 16 + ih);
        short8 a3 = *(const short8*)(xb + (size_t)(base + 3 * 16 + 2 * ks) * 16 + ih);
        acc[0][0] = __builtin_amdgcn_mfma_f32_16x16x32_bf16(a0, B0[ks], acc[0][0], 0, 0, 0);
        acc[0][1] = __builtin_amdgcn_mfma_f32_16x16x32_bf16(a0, B1[ks], acc[0][1], 0, 0, 0);
        acc[1][0] = __builtin_amdgcn_mfma_f32_16x16x32_bf16(a1, B0[ks], acc[1][0], 0, 0, 0);
        acc[1][1] = __builtin_amdgcn_mfma_f32_16x16x32_bf16(a1, B1[ks], acc[1][1], 0, 0, 0);
        acc[2][0] = __builtin_amdgcn_mfma_f32_16x16x32_bf16(a2, B0[ks], acc[2][0], 0, 0, 0);
        acc[2][1] = __builtin_amdgcn_mfma_f32_16x16x32_bf16(a2, B1[ks], acc[2][1], 0, 0, 0);
        acc[3][0] = __builtin_amdgcn_mfma_f32_16x16x32_bf16(a3, B0[ks], acc[3][0], 0, 0, 0);
        acc[3][1] = __builtin_amdgcn_mfma_f32_16x16x32_bf16(a3, B1[ks], acc[3][1], 0, 0, 0);
    }

    // epilogue: C col = lane&15 (j), row = quad*4+reg; block 0 skips t<9 (head owns them)
    long outb = (long)b * T_;
    float bc0 = bcg[m];
    float bc1 = (m < 8) ? bcg[16 + m] : 0.f;
    bool edge = (blockIdx.x == 0);
#pragma unroll
    for (int mt = 0; mt < 4; ++mt) {
        int trow = t0 + w * 64 + mt * 16 + quad * 4;
#pragma unroll
        for (int reg = 0; reg < 4; ++reg) {
            int t = trow + reg;
            if (!edge || t >= 9) {
                float* o = out + (outb + t) * OUT_;
                o[m] = acc[mt][0][reg] + bc0;
                if (m < 8) o[16 + m] = acc[mt][1][reg] + bc1;
            }
        }
    }
}

extern "C" void kernel_launch(void* const* d_in, const int* in_sizes, int n_in,
                              void* d_out, int out_size, void* d_ws, size_t ws_size,
                              hipStream_t stream) {
    const float* x  = (const float*)d_in[0];
    const float* w1 = (const float*)d_in[1];
    const float* b1 = (const float*)d_in[2];
    const float* wf = (const float*)d_in[3];
    const float* bf = (const float*)d_in[4];
    float* out = (float*)d_out;
    unsigned short* w2pk = (unsigned short*)d_ws;
    float* bcg = (float*)((char*)d_ws + WS_BC_OFF);
    float* Eg  = (float*)((char*)d_ws + WS_E_OFF);
    float* w1t = (float*)((char*)d_ws + WS_W1T_OFF);
    unsigned short* xbf = (unsigned short*)((char*)d_ws + WS_XBF_OFF);

    hipLaunchKernelGGL(pre_kernel, dim3(1148), dim3(256), 0, stream,
                       x, w1, xbf, w1t, w2pk);
    hipLaunchKernelGGL(prep_kernel, dim3(606), dim3(256), 0, stream,
                       w1t, b1, wf, bf, w2pk, bcg, Eg);
    hipLaunchKernelGGL(main_kernel, dim3(33, B_), dim3(256), 0, stream,
                       xbf, w2pk, bcg, out, x, Eg);
}

// Round 9
// 99.315 us; speedup vs baseline: 4.4571x; 1.0295x over previous
//
#include <hip/hip_runtime.h>

#define B_   32
#define T_   8192
#define F_   16
#define OUT_ 24
#define K1_  10
#define ND   19            // combined kernel width
#define JP   32            // padded N
#define PADL 24            // zeroed pad rows before t=0 in xlo/xhi
#define XROWS_TOT (PADL + T_ + 8)   // 8224 rows per batch
#define TB   512           // timesteps per main block
#define WROWS 536          // staged window rows: [t0-18, t0+TB+1] + slack

// ws layout (bytes):
// [0, 20480)            w2pk: bf16 packed W-frags [tbl=2][ks=10][lane=64][z=8]
// [20480, 20576)        Bc fp32[24]
// [20576, 144992)       E fp32[9][24][9][16]
// [144992, 226912)      w1t fp32[(k*16+i)*128 + c]
// [226944, +4210688)    xlo bf16 [32][8224][8]   (lo half-rows, zero-padded)
// [4437632, +4210688)   xhi bf16 [32][8224][8]
#define WS_BC_OFF   20480
#define WS_E_OFF    20576
#define WS_W1T_OFF  144992
#define WS_XLO_OFF  226944
#define WS_XHI_OFF  (WS_XLO_OFF + B_ * XROWS_TOT * 8 * 2)

typedef short short8 __attribute__((ext_vector_type(8)));
typedef float float4v __attribute__((ext_vector_type(4)));

__device__ __forceinline__ unsigned short f2bf(float f) {
    unsigned u = __builtin_bit_cast(unsigned, f);
    unsigned r = (u + 0x7fffu + ((u >> 16) & 1u)) >> 16;  // RNE
    return (unsigned short)r;
}

__device__ __forceinline__ short8 cvt8(float4 f0, float4 f1) {
    short8 v;
    v[0] = (short)f2bf(f0.x); v[1] = (short)f2bf(f0.y);
    v[2] = (short)f2bf(f0.z); v[3] = (short)f2bf(f0.w);
    v[4] = (short)f2bf(f1.x); v[5] = (short)f2bf(f1.y);
    v[6] = (short)f2bf(f1.z); v[7] = (short)f2bf(f1.w);
    return v;
}

// ---------------- pre: xlo/xhi (blocks 0..1027) + w1t (1028..1107) + w2pk zero (1108..1147)
__global__ __launch_bounds__(256) void pre_kernel(const float* __restrict__ x,
                                                  const float* __restrict__ w1,
                                                  unsigned short* __restrict__ xlo,
                                                  unsigned short* __restrict__ xhi,
                                                  float* __restrict__ w1t,
                                                  unsigned short* __restrict__ w2pk) {
    int bx = blockIdx.x;
    int tid = threadIdx.x;
    if (bx < 1028) {
        int id = bx * 256 + tid;                 // one row per thread
        if (id >= B_ * XROWS_TOT) return;
        int b = id / XROWS_TOT, r = id - b * XROWS_TOT;
        int t = r - PADL;
        short8 v0 = short8{0,0,0,0,0,0,0,0}, v1 = v0;
        if (t >= 0 && t < T_) {
            const float4* p = (const float4*)(x + ((long)b * T_ + t) * 16);
            float4 f0 = p[0], f1 = p[1], f2 = p[2], f3 = p[3];
            v0 = cvt8(f0, f1);
            v1 = cvt8(f2, f3);
        }
        *(short8*)(xlo + (size_t)id * 8) = v0;
        *(short8*)(xhi + (size_t)id * 8) = v1;
    } else if (bx < 1108) {
        int idx = (bx - 1028) * 256 + tid;       // 20480 elems
        float v = w1[idx];
        int c = idx / 160;
        int rem = idx - c * 160;
        int i = rem / 10;
        int k = rem - i * 10;
        w1t[(k * 16 + i) * 128 + c] = v;
    } else {
        int idx = (bx - 1108) * 256 + tid;       // 10240 uints
        ((unsigned*)w2pk)[idx] = 0;
    }
}

// ---------------- prep: wave-per-task, no barriers.
// waves 0..455: W2(j,d); 456..479: Bc(j); 480..2423: E(t,j,tau). grid 606 x 256.
__global__ __launch_bounds__(256) void prep_kernel(const float* __restrict__ w1t,
                                                   const float* __restrict__ b1,
                                                   const float* __restrict__ wf,
                                                   const float* __restrict__ bf,
                                                   unsigned short* __restrict__ w2pk,
                                                   float* __restrict__ bcg,
                                                   float* __restrict__ Eg) {
    int tid = threadIdx.x;
    int lane = tid & 63;
    int wid = blockIdx.x * 4 + (tid >> 6);

    if (wid < 456) {
        int j = wid / ND, d = wid % ND;
        float p[16];
#pragma unroll
        for (int i = 0; i < 16; ++i) p[i] = 0.f;
        int klo = d - 9 > 0 ? d - 9 : 0;
        int khi = d < 9 ? d : 9;
        for (int k = klo; k <= khi; ++k) {
            float w0 = wf[j * 1280 + k * 128 + lane];
            float w1v = wf[j * 1280 + k * 128 + 64 + lane];
            const float* wb = w1t + (d - k) * 16 * 128;
#pragma unroll
            for (int i = 0; i < 16; ++i)
                p[i] = fmaf(w0, wb[i * 128 + lane], fmaf(w1v, wb[i * 128 + 64 + lane], p[i]));
        }
#pragma unroll
        for (int i = 0; i < 16; ++i) {
            p[i] += __shfl_xor(p[i], 1);
            p[i] += __shfl_xor(p[i], 2);
            p[i] += __shfl_xor(p[i], 4);
            p[i] += __shfl_xor(p[i], 8);
            p[i] += __shfl_xor(p[i], 16);
            p[i] += __shfl_xor(p[i], 32);
        }
        if (lane < 16) {
            float v = p[0];
#pragma unroll
            for (int i = 1; i < 16; ++i)
                if (lane == i) v = p[i];
            int kk = d * 16 + lane;
            int ks = kk >> 5, r = kk & 31;
            int quad = r >> 3, z = r & 7;
            int tbl = j >> 4, jj = j & 15;
            int lt = jj + quad * 16;
            w2pk[((tbl * 10 + ks) * 64 + lt) * 8 + z] = f2bf(v);
        }
    } else if (wid < 480) {
        int j = wid - 456;
        float s0 = 0.f, s1 = 0.f;
#pragma unroll
        for (int k = 0; k < K1_; ++k) {
            s0 += wf[j * 1280 + k * 128 + lane];
            s1 += wf[j * 1280 + k * 128 + 64 + lane];
        }
        float s = s0 * b1[lane] + s1 * b1[64 + lane];
        s += __shfl_xor(s, 1);
        s += __shfl_xor(s, 2);
        s += __shfl_xor(s, 4);
        s += __shfl_xor(s, 8);
        s += __shfl_xor(s, 16);
        s += __shfl_xor(s, 32);
        if (lane == 0) bcg[j] = bf[j] + s;
    } else {
        int eidx = wid - 480;                 // 0..1943
        int t = eidx / 216;
        int rem = eidx % 216;
        int j = rem / 9, tau = rem % 9;
        float p[16];
#pragma unroll
        for (int i = 0; i < 16; ++i) p[i] = 0.f;
        for (int k = 0; k < K1_; ++k) {
            int u = t + k - 9; if (u < 0) u = 0;
            if (tau > u) continue;
            int kap = tau + 9 - u;
            float w0 = wf[j * 1280 + k * 128 + lane];
            float w1v = wf[j * 1280 + k * 128 + 64 + lane];
            const float* wb = w1t + kap * 16 * 128;
#pragma unroll
            for (int i = 0; i < 16; ++i)
                p[i] = fmaf(w0, wb[i * 128 + lane], fmaf(w1v, wb[i * 128 + 64 + lane], p[i]));
        }
#pragma unroll
        for (int i = 0; i < 16; ++i) {
            p[i] += __shfl_xor(p[i], 1);
            p[i] += __shfl_xor(p[i], 2);
            p[i] += __shfl_xor(p[i], 4);
            p[i] += __shfl_xor(p[i], 8);
            p[i] += __shfl_xor(p[i], 16);
            p[i] += __shfl_xor(p[i], 32);
        }
        if (lane < 16) {
            float v = p[0];
#pragma unroll
            for (int i = 1; i < 16; ++i)
                if (lane == i) v = p[i];
            Eg[((t * OUT_ + j) * 9 + tau) * 16 + lane] = v;
        }
    }
}

// ---------------- main: transposed MFMA GEMM (W=A, x=B), x staged in LDS.
// grid (17, 32): x=0..15 GEMM over 512 t each; x==16 head (t<9).
__global__ __launch_bounds__(256, 2) void main_kernel(const unsigned short* __restrict__ xlo,
                                                      const unsigned short* __restrict__ xhi,
                                                      const unsigned short* __restrict__ w2pk,
                                                      const float* __restrict__ bcg,
                                                      float* __restrict__ out,
                                                      const float* __restrict__ x,
                                                      const float* __restrict__ Eg) {
    int tid = threadIdx.x;
    int b = blockIdx.y;

    if (blockIdx.x == 16) {    // head: t in [0,9)
        if (tid >= 9 * OUT_) return;
        int t = tid / OUT_, j = tid % OUT_;
        const float4* xv = (const float4*)(x + (long)b * T_ * F_);
        const float4* ev = (const float4*)(Eg + (long)tid * 144);
        float ax = 0.f, ay = 0.f, az = 0.f, aw = 0.f;
#pragma unroll
        for (int q = 0; q < 36; ++q) {
            float4 e = ev[q];
            float4 v = xv[q];
            ax = fmaf(e.x, v.x, ax);
            ay = fmaf(e.y, v.y, ay);
            az = fmaf(e.z, v.z, az);
            aw = fmaf(e.w, v.w, aw);
        }
        out[((long)b * T_ + t) * OUT_ + j] = bcg[j] + ((ax + ay) + (az + aw));
        return;
    }

    __shared__ short xls[2 * WROWS * 8];   // 17152 B: [h][row][8] bf16
    int t0 = blockIdx.x * TB;
    int gbase = PADL + t0 - 18;            // >= 6

    // stage x window (coalesced global, stride-1 ds_write_b128)
    for (int idx = tid; idx < 2 * WROWS; idx += 256) {
        int h = idx >= WROWS;
        int row = h ? idx - WROWS : idx;
        const unsigned short* src = (h ? xhi : xlo) + ((size_t)b * XROWS_TOT + gbase + row) * 8;
        short8 v = *(const short8*)src;
        *(short8*)(xls + (h * WROWS + row) * 8) = v;
    }

    int lane = tid & 63, w = tid >> 6;
    int t = lane & 15, q = lane >> 4;
    int h = q & 1, qh = q >> 1;

    // W A-frags: read once per wave (coalesced 1KB loads, L1-hot)
    const unsigned short* pk0 = w2pk + lane * 8;          // tbl0: j = 0..15
    const unsigned short* pk1 = w2pk + 5120 + lane * 8;   // tbl1: j = 16..31
    short8 W0[10], W1[10];
#pragma unroll
    for (int ks = 0; ks < 10; ++ks) {
        W0[ks] = *(const short8*)(pk0 + ks * 512);
        W1[ks] = *(const short8*)(pk1 + ks * 512);
    }

    __syncthreads();

    const short* ap = xls + (h * WROWS + w * 128 + t + qh) * 8;

    float4v acc[8][2];
#pragma unroll
    for (int mt = 0; mt < 8; ++mt) {
        acc[mt][0] = float4v{0.f, 0.f, 0.f, 0.f};
        acc[mt][1] = float4v{0.f, 0.f, 0.f, 0.f};
    }

#pragma unroll
    for (int ks = 0; ks < 10; ++ks) {
#pragma unroll
        for (int mt = 0; mt < 8; ++mt) {
            short8 xf = *(const short8*)(ap + (mt * 16 + 2 * ks) * 8);
            acc[mt][0] = __builtin_amdgcn_mfma_f32_16x16x32_bf16(W0[ks], xf, acc[mt][0], 0, 0, 0);
            acc[mt][1] = __builtin_amdgcn_mfma_f32_16x16x32_bf16(W1[ks], xf, acc[mt][1], 0, 0, 0);
        }
    }

    // epilogue: C col = t, row = j = q*4+reg (+16 for tbl1) -> float4 stores
    long outb = (long)b * T_;
    float4 bc0 = *(const float4*)(bcg + q * 4);
    float4 bc1 = (q < 2) ? *(const float4*)(bcg + 16 + q * 4) : make_float4(0.f, 0.f, 0.f, 0.f);
    bool edge = (blockIdx.x == 0);
#pragma unroll
    for (int mt = 0; mt < 8; ++mt) {
        int t_out = t0 + w * 128 + mt * 16 + t;
        if (!edge || t_out >= 9) {        // t<9 owned by head
            float* o = out + (outb + t_out) * OUT_;
            float4 v0 = make_float4(acc[mt][0][0] + bc0.x, acc[mt][0][1] + bc0.y,
                                    acc[mt][0][2] + bc0.z, acc[mt][0][3] + bc0.w);
            *(float4*)(o + q * 4) = v0;
            if (q < 2) {
                float4 v1 = make_float4(acc[mt][1][0] + bc1.x, acc[mt][1][1] + bc1.y,
                                        acc[mt][1][2] + bc1.z, acc[mt][1][3] + bc1.w);
                *(float4*)(o + 16 + q * 4) = v1;
            }
        }
    }
}

extern "C" void kernel_launch(void* const* d_in, const int* in_sizes, int n_in,
                              void* d_out, int out_size, void* d_ws, size_t ws_size,
                              hipStream_t stream) {
    const float* x  = (const float*)d_in[0];
    const float* w1 = (const float*)d_in[1];
    const float* b1 = (const float*)d_in[2];
    const float* wf = (const float*)d_in[3];
    const float* bf = (const float*)d_in[4];
    float* out = (float*)d_out;
    unsigned short* w2pk = (unsigned short*)d_ws;
    float* bcg = (float*)((char*)d_ws + WS_BC_OFF);
    float* Eg  = (float*)((char*)d_ws + WS_E_OFF);
    float* w1t = (float*)((char*)d_ws + WS_W1T_OFF);
    unsigned short* xlo = (unsigned short*)((char*)d_ws + WS_XLO_OFF);
    unsigned short* xhi = (unsigned short*)((char*)d_ws + WS_XHI_OFF);

    hipLaunchKernelGGL(pre_kernel, dim3(1148), dim3(256), 0, stream,
                       x, w1, xlo, xhi, w1t, w2pk);
    hipLaunchKernelGGL(prep_kernel, dim3(606), dim3(256), 0, stream,
                       w1t, b1, wf, bf, w2pk, bcg, Eg);
    hipLaunchKernelGGL(main_kernel, dim3(17, B_), dim3(256), 0, stream,
                       xlo, xhi, w2pk, bcg, out, x, Eg);
}

// Round 10
// 98.830 us; speedup vs baseline: 4.4790x; 1.0049x over previous
//
#include <hip/hip_runtime.h>

#define B_   32
#define T_   8192
#define F_   16
#define OUT_ 24
#define K1_  10
#define ND   19            // combined kernel width
#define JP   32            // padded N
#define TB   512           // timesteps per main block
#define WROWS 536          // staged window rows: [t0-18, t0+TB+1] + slack
#define H1OFF (WROWS * 8 + 8)   // hi-half LDS offset in shorts (+16B de-alias)

// ws layout (bytes):
// [0, 20480)            w2pk: bf16 packed W-frags [tbl=2][ks=10][lane=64][z=8]
// [20480, 20576)        Bc fp32[24]
// [20576, 144992)       E fp32[9][24][9][16]
// [144992, 226912)      w1t fp32[(k*16+i)*128 + c]
#define WS_BC_OFF   20480
#define WS_E_OFF    20576
#define WS_W1T_OFF  144992

typedef short short8 __attribute__((ext_vector_type(8)));
typedef float float4v __attribute__((ext_vector_type(4)));

__device__ __forceinline__ unsigned short f2bf(float f) {
    unsigned u = __builtin_bit_cast(unsigned, f);
    unsigned r = (u + 0x7fffu + ((u >> 16) & 1u)) >> 16;  // RNE
    return (unsigned short)r;
}

__device__ __forceinline__ short8 cvt8(float4 f0, float4 f1) {
    short8 v;
    v[0] = (short)f2bf(f0.x); v[1] = (short)f2bf(f0.y);
    v[2] = (short)f2bf(f0.z); v[3] = (short)f2bf(f0.w);
    v[4] = (short)f2bf(f1.x); v[5] = (short)f2bf(f1.y);
    v[6] = (short)f2bf(f1.z); v[7] = (short)f2bf(f1.w);
    return v;
}

// ---------------- pre (tiny): w1t transpose (blocks 0..79) + w2pk zero (80..119)
__global__ __launch_bounds__(256) void pre_kernel(const float* __restrict__ w1,
                                                  float* __restrict__ w1t,
                                                  unsigned short* __restrict__ w2pk) {
    int bx = blockIdx.x;
    int tid = threadIdx.x;
    if (bx < 80) {
        int idx = bx * 256 + tid;                // 20480 elems
        float v = w1[idx];
        int c = idx / 160;
        int rem = idx - c * 160;
        int i = rem / 10;
        int k = rem - i * 10;
        w1t[(k * 16 + i) * 128 + c] = v;
    } else {
        int idx = (bx - 80) * 256 + tid;         // 10240 uints
        ((unsigned*)w2pk)[idx] = 0;
    }
}

// ---------------- prep: wave-per-task, no barriers.
// waves 0..455: W2(j,d); 456..479: Bc(j); 480..2423: E(t,j,tau). grid 606 x 256.
__global__ __launch_bounds__(256) void prep_kernel(const float* __restrict__ w1t,
                                                   const float* __restrict__ b1,
                                                   const float* __restrict__ wf,
                                                   const float* __restrict__ bf,
                                                   unsigned short* __restrict__ w2pk,
                                                   float* __restrict__ bcg,
                                                   float* __restrict__ Eg) {
    int tid = threadIdx.x;
    int lane = tid & 63;
    int wid = blockIdx.x * 4 + (tid >> 6);

    if (wid < 456) {
        int j = wid / ND, d = wid % ND;
        float p[16];
#pragma unroll
        for (int i = 0; i < 16; ++i) p[i] = 0.f;
        int klo = d - 9 > 0 ? d - 9 : 0;
        int khi = d < 9 ? d : 9;
        for (int k = klo; k <= khi; ++k) {
            float w0 = wf[j * 1280 + k * 128 + lane];
            float w1v = wf[j * 1280 + k * 128 + 64 + lane];
            const float* wb = w1t + (d - k) * 16 * 128;
#pragma unroll
            for (int i = 0; i < 16; ++i)
                p[i] = fmaf(w0, wb[i * 128 + lane], fmaf(w1v, wb[i * 128 + 64 + lane], p[i]));
        }
#pragma unroll
        for (int i = 0; i < 16; ++i) {
            p[i] += __shfl_xor(p[i], 1);
            p[i] += __shfl_xor(p[i], 2);
            p[i] += __shfl_xor(p[i], 4);
            p[i] += __shfl_xor(p[i], 8);
            p[i] += __shfl_xor(p[i], 16);
            p[i] += __shfl_xor(p[i], 32);
        }
        if (lane < 16) {
            float v = p[0];
#pragma unroll
            for (int i = 1; i < 16; ++i)
                if (lane == i) v = p[i];
            int kk = d * 16 + lane;
            int ks = kk >> 5, r = kk & 31;
            int quad = r >> 3, z = r & 7;
            int tbl = j >> 4, jj = j & 15;
            int lt = jj + quad * 16;
            w2pk[((tbl * 10 + ks) * 64 + lt) * 8 + z] = f2bf(v);
        }
    } else if (wid < 480) {
        int j = wid - 456;
        float s0 = 0.f, s1 = 0.f;
#pragma unroll
        for (int k = 0; k < K1_; ++k) {
            s0 += wf[j * 1280 + k * 128 + lane];
            s1 += wf[j * 1280 + k * 128 + 64 + lane];
        }
        float s = s0 * b1[lane] + s1 * b1[64 + lane];
        s += __shfl_xor(s, 1);
        s += __shfl_xor(s, 2);
        s += __shfl_xor(s, 4);
        s += __shfl_xor(s, 8);
        s += __shfl_xor(s, 16);
        s += __shfl_xor(s, 32);
        if (lane == 0) bcg[j] = bf[j] + s;
    } else {
        int eidx = wid - 480;                 // 0..1943
        int t = eidx / 216;
        int rem = eidx % 216;
        int j = rem / 9, tau = rem % 9;
        float p[16];
#pragma unroll
        for (int i = 0; i < 16; ++i) p[i] = 0.f;
        for (int k = 0; k < K1_; ++k) {
            int u = t + k - 9; if (u < 0) u = 0;
            if (tau > u) continue;
            int kap = tau + 9 - u;
            float w0 = wf[j * 1280 + k * 128 + lane];
            float w1v = wf[j * 1280 + k * 128 + 64 + lane];
            const float* wb = w1t + kap * 16 * 128;
#pragma unroll
            for (int i = 0; i < 16; ++i)
                p[i] = fmaf(w0, wb[i * 128 + lane], fmaf(w1v, wb[i * 128 + 64 + lane], p[i]));
        }
#pragma unroll
        for (int i = 0; i < 16; ++i) {
            p[i] += __shfl_xor(p[i], 1);
            p[i] += __shfl_xor(p[i], 2);
            p[i] += __shfl_xor(p[i], 4);
            p[i] += __shfl_xor(p[i], 8);
            p[i] += __shfl_xor(p[i], 16);
            p[i] += __shfl_xor(p[i], 32);
        }
        if (lane < 16) {
            float v = p[0];
#pragma unroll
            for (int i = 1; i < 16; ++i)
                if (lane == i) v = p[i];
            Eg[((t * OUT_ + j) * 9 + tau) * 16 + lane] = v;
        }
    }
}

// ---------------- main: transposed MFMA GEMM (W=A, x=B), fused fp32->bf16 LDS staging.
// grid (17, 32): x=0..15 GEMM over 512 t each; x==16 head (t<9).
__global__ __launch_bounds__(256) void main_kernel(const float* __restrict__ x,
                                                   const unsigned short* __restrict__ w2pk,
                                                   const float* __restrict__ bcg,
                                                   float* __restrict__ out,
                                                   const float* __restrict__ Eg) {
    int tid = threadIdx.x;
    int b = blockIdx.y;

    if (blockIdx.x == 16) {    // head: t in [0,9)
        if (tid >= 9 * OUT_) return;
        int t = tid / OUT_, j = tid % OUT_;
        const float4* xv = (const float4*)(x + (long)b * T_ * F_);
        const float4* ev = (const float4*)(Eg + (long)tid * 144);
        float ax = 0.f, ay = 0.f, az = 0.f, aw = 0.f;
#pragma unroll
        for (int q = 0; q < 36; ++q) {
            float4 e = ev[q];
            float4 v = xv[q];
            ax = fmaf(e.x, v.x, ax);
            ay = fmaf(e.y, v.y, ay);
            az = fmaf(e.z, v.z, az);
            aw = fmaf(e.w, v.w, aw);
        }
        out[((long)b * T_ + t) * OUT_ + j] = bcg[j] + ((ax + ay) + (az + aw));
        return;
    }

    __shared__ short xls[2 * WROWS * 8 + 8];   // 17168 B: lo-half @0, hi-half @H1OFF
    int t0 = blockIdx.x * TB;

    // stage x window: global fp32 (coalesced) -> bf16 -> LDS; zero outside [0,T)
    for (int idx = tid; idx < 2 * WROWS; idx += 256) {
        int h = idx >= WROWS;
        int row = h ? idx - WROWS : idx;
        int t = t0 - 18 + row;
        short8 v = short8{0, 0, 0, 0, 0, 0, 0, 0};
        if (t >= 0 && t < T_) {
            const float4* p = (const float4*)(x + ((long)b * T_ + t) * 16 + h * 8);
            v = cvt8(p[0], p[1]);
        }
        *(short8*)(xls + h * H1OFF + row * 8) = v;
    }

    int lane = tid & 63, w = tid >> 6;
    int t = lane & 15, q = lane >> 4;
    int h = q & 1, qh = q >> 1;

    // W A-frags: read once per wave (coalesced 1KB loads, L1-hot)
    const unsigned short* pk0 = w2pk + lane * 8;          // tbl0: j = 0..15
    const unsigned short* pk1 = w2pk + 5120 + lane * 8;   // tbl1: j = 16..31
    short8 W0[10], W1[10];
#pragma unroll
    for (int ks = 0; ks < 10; ++ks) {
        W0[ks] = *(const short8*)(pk0 + ks * 512);
        W1[ks] = *(const short8*)(pk1 + ks * 512);
    }

    __syncthreads();

    const short* ap = xls + h * H1OFF + (w * 128 + t + qh) * 8;

    float4v acc[8][2];
#pragma unroll
    for (int mt = 0; mt < 8; ++mt) {
        acc[mt][0] = float4v{0.f, 0.f, 0.f, 0.f};
        acc[mt][1] = float4v{0.f, 0.f, 0.f, 0.f};
    }

#pragma unroll
    for (int ks = 0; ks < 10; ++ks) {
#pragma unroll
        for (int mt = 0; mt < 8; ++mt) {
            short8 xf = *(const short8*)(ap + (mt * 16 + 2 * ks) * 8);
            acc[mt][0] = __builtin_amdgcn_mfma_f32_16x16x32_bf16(W0[ks], xf, acc[mt][0], 0, 0, 0);
            acc[mt][1] = __builtin_amdgcn_mfma_f32_16x16x32_bf16(W1[ks], xf, acc[mt][1], 0, 0, 0);
        }
    }

    // epilogue: C col = t, row = j = q*4+reg (+16 for tbl1) -> float4 stores
    long outb = (long)b * T_;
    float4 bc0 = *(const float4*)(bcg + q * 4);
    float4 bc1 = (q < 2) ? *(const float4*)(bcg + 16 + q * 4) : make_float4(0.f, 0.f, 0.f, 0.f);
    bool edge = (blockIdx.x == 0);
#pragma unroll
    for (int mt = 0; mt < 8; ++mt) {
        int t_out = t0 + w * 128 + mt * 16 + t;
        if (!edge || t_out >= 9) {        // t<9 owned by head
            float* o = out + (outb + t_out) * OUT_;
            float4 v0 = make_float4(acc[mt][0][0] + bc0.x, acc[mt][0][1] + bc0.y,
                                    acc[mt][0][2] + bc0.z, acc[mt][0][3] + bc0.w);
            *(float4*)(o + q * 4) = v0;
            if (q < 2) {
                float4 v1 = make_float4(acc[mt][1][0] + bc1.x, acc[mt][1][1] + bc1.y,
                                        acc[mt][1][2] + bc1.z, acc[mt][1][3] + bc1.w);
                *(float4*)(o + 16 + q * 4) = v1;
            }
        }
    }
}

extern "C" void kernel_launch(void* const* d_in, const int* in_sizes, int n_in,
                              void* d_out, int out_size, void* d_ws, size_t ws_size,
                              hipStream_t stream) {
    const float* x  = (const float*)d_in[0];
    const float* w1 = (const float*)d_in[1];
    const float* b1 = (const float*)d_in[2];
    const float* wf = (const float*)d_in[3];
    const float* bf = (const float*)d_in[4];
    float* out = (float*)d_out;
    unsigned short* w2pk = (unsigned short*)d_ws;
    float* bcg = (float*)((char*)d_ws + WS_BC_OFF);
    float* Eg  = (float*)((char*)d_ws + WS_E_OFF);
    float* w1t = (float*)((char*)d_ws + WS_W1T_OFF);

    hipLaunchKernelGGL(pre_kernel, dim3(120), dim3(256), 0, stream, w1, w1t, w2pk);
    hipLaunchKernelGGL(prep_kernel, dim3(606), dim3(256), 0, stream,
                       w1t, b1, wf, bf, w2pk, bcg, Eg);
    hipLaunchKernelGGL(main_kernel, dim3(17, B_), dim3(256), 0, stream,
                       x, w2pk, bcg, out, Eg);
}

// Round 13
// 98.332 us; speedup vs baseline: 4.5017x; 1.0051x over previous
//
#include <hip/hip_runtime.h>

#define B_   32
#define T_   8192
#define F_   16
#define OUT_ 24
#define K1_  10
#define ND   19            // combined kernel width
#define JP   32            // padded N
#define TB   512           // timesteps per main block
#define WROWS 536          // staged window rows: [t0-18, t0+TB+1] + slack
#define H1OFF (WROWS * 8 + 8)   // hi-half LDS offset in shorts (+16B de-alias)

// ws layout (bytes):
// [0, 20480)            w2pk: bf16 packed W-frags [tbl=2][ks=10][lane=64][z=8]
// [20480, 20576)        Bc fp32[24]
// [20576, 144992)       E fp32[9][24][9][16]
// [144992, 226912)      w1t fp32[(k*16+i)*128 + c]
#define WS_BC_OFF   20480
#define WS_E_OFF    20576
#define WS_W1T_OFF  144992

typedef short short8 __attribute__((ext_vector_type(8)));
typedef float float4v __attribute__((ext_vector_type(4)));

__device__ __forceinline__ unsigned short f2bf(float f) {
    unsigned u = __builtin_bit_cast(unsigned, f);
    unsigned r = (u + 0x7fffu + ((u >> 16) & 1u)) >> 16;  // RNE
    return (unsigned short)r;
}

__device__ __forceinline__ short8 cvt8(float4 f0, float4 f1) {
    short8 v;
    v[0] = (short)f2bf(f0.x); v[1] = (short)f2bf(f0.y);
    v[2] = (short)f2bf(f0.z); v[3] = (short)f2bf(f0.w);
    v[4] = (short)f2bf(f1.x); v[5] = (short)f2bf(f1.y);
    v[6] = (short)f2bf(f1.z); v[7] = (short)f2bf(f1.w);
    return v;
}

// ---------------- pre (tiny): w1t transpose (blocks 0..79) + w2pk zero (80..119)
__global__ __launch_bounds__(256) void pre_kernel(const float* __restrict__ w1,
                                                  float* __restrict__ w1t,
                                                  unsigned short* __restrict__ w2pk) {
    int bx = blockIdx.x;
    int tid = threadIdx.x;
    if (bx < 80) {
        int idx = bx * 256 + tid;                // 20480 elems
        float v = w1[idx];
        int c = idx / 160;
        int rem = idx - c * 160;
        int i = rem / 10;
        int k = rem - i * 10;
        w1t[(k * 16 + i) * 128 + c] = v;
    } else {
        int idx = (bx - 80) * 256 + tid;         // 10240 uints
        ((unsigned*)w2pk)[idx] = 0;
    }
}

// ---------------- prep: wave-per-task, no barriers.
// waves 0..455: W2(j,d); 456..479: Bc(j); 480..2423: E(t,j,tau). grid 606 x 256.
__global__ __launch_bounds__(256) void prep_kernel(const float* __restrict__ w1t,
                                                   const float* __restrict__ b1,
                                                   const float* __restrict__ wf,
                                                   const float* __restrict__ bf,
                                                   unsigned short* __restrict__ w2pk,
                                                   float* __restrict__ bcg,
                                                   float* __restrict__ Eg) {
    int tid = threadIdx.x;
    int lane = tid & 63;
    int wid = blockIdx.x * 4 + (tid >> 6);

    if (wid < 456) {
        int j = wid / ND, d = wid % ND;
        float p[16];
#pragma unroll
        for (int i = 0; i < 16; ++i) p[i] = 0.f;
        int klo = d - 9 > 0 ? d - 9 : 0;
        int khi = d < 9 ? d : 9;
        for (int k = klo; k <= khi; ++k) {
            float w0 = wf[j * 1280 + k * 128 + lane];
            float w1v = wf[j * 1280 + k * 128 + 64 + lane];
            const float* wb = w1t + (d - k) * 16 * 128;
#pragma unroll
            for (int i = 0; i < 16; ++i)
                p[i] = fmaf(w0, wb[i * 128 + lane], fmaf(w1v, wb[i * 128 + 64 + lane], p[i]));
        }
#pragma unroll
        for (int i = 0; i < 16; ++i) {
            p[i] += __shfl_xor(p[i], 1);
            p[i] += __shfl_xor(p[i], 2);
            p[i] += __shfl_xor(p[i], 4);
            p[i] += __shfl_xor(p[i], 8);
            p[i] += __shfl_xor(p[i], 16);
            p[i] += __shfl_xor(p[i], 32);
        }
        if (lane < 16) {
            float v = p[0];
#pragma unroll
            for (int i = 1; i < 16; ++i)
                if (lane == i) v = p[i];
            int kk = d * 16 + lane;
            int ks = kk >> 5, r = kk & 31;
            int quad = r >> 3, z = r & 7;
            int tbl = j >> 4, jj = j & 15;
            int lt = jj + quad * 16;
            w2pk[((tbl * 10 + ks) * 64 + lt) * 8 + z] = f2bf(v);
        }
    } else if (wid < 480) {
        int j = wid - 456;
        float s0 = 0.f, s1 = 0.f;
#pragma unroll
        for (int k = 0; k < K1_; ++k) {
            s0 += wf[j * 1280 + k * 128 + lane];
            s1 += wf[j * 1280 + k * 128 + 64 + lane];
        }
        float s = s0 * b1[lane] + s1 * b1[64 + lane];
        s += __shfl_xor(s, 1);
        s += __shfl_xor(s, 2);
        s += __shfl_xor(s, 4);
        s += __shfl_xor(s, 8);
        s += __shfl_xor(s, 16);
        s += __shfl_xor(s, 32);
        if (lane == 0) bcg[j] = bf[j] + s;
    } else {
        int eidx = wid - 480;                 // 0..1943
        int t = eidx / 216;
        int rem = eidx % 216;
        int j = rem / 9, tau = rem % 9;
        float p[16];
#pragma unroll
        for (int i = 0; i < 16; ++i) p[i] = 0.f;
        for (int k = 0; k < K1_; ++k) {
            int u = t + k - 9; if (u < 0) u = 0;
            if (tau > u) continue;
            int kap = tau + 9 - u;
            float w0 = wf[j * 1280 + k * 128 + lane];
            float w1v = wf[j * 1280 + k * 128 + 64 + lane];
            const float* wb = w1t + kap * 16 * 128;
#pragma unroll
            for (int i = 0; i < 16; ++i)
                p[i] = fmaf(w0, wb[i * 128 + lane], fmaf(w1v, wb[i * 128 + 64 + lane], p[i]));
        }
#pragma unroll
        for (int i = 0; i < 16; ++i) {
            p[i] += __shfl_xor(p[i], 1);
            p[i] += __shfl_xor(p[i], 2);
            p[i] += __shfl_xor(p[i], 4);
            p[i] += __shfl_xor(p[i], 8);
            p[i] += __shfl_xor(p[i], 16);
            p[i] += __shfl_xor(p[i], 32);
        }
        if (lane < 16) {
            float v = p[0];
#pragma unroll
            for (int i = 1; i < 16; ++i)
                if (lane == i) v = p[i];
            Eg[((t * OUT_ + j) * 9 + tau) * 16 + lane] = v;
        }
    }
}

// ---------------- main: transposed MFMA GEMM (W=A, x=B), fused fp32->bf16 LDS staging.
// grid (17, 32): x=0..15 GEMM over 512 t each; x==16 head (t<9).
__global__ __launch_bounds__(256) void main_kernel(const float* __restrict__ x,
                                                   const unsigned short* __restrict__ w2pk,
                                                   const float* __restrict__ bcg,
                                                   float* __restrict__ out,
                                                   const float* __restrict__ Eg) {
    int tid = threadIdx.x;
    int b = blockIdx.y;

    if (blockIdx.x == 16) {    // head: t in [0,9)
        if (tid >= 9 * OUT_) return;
        int t = tid / OUT_, j = tid % OUT_;
        const float4* xv = (const float4*)(x + (long)b * T_ * F_);
        const float4* ev = (const float4*)(Eg + (long)tid * 144);
        float ax = 0.f, ay = 0.f, az = 0.f, aw = 0.f;
#pragma unroll
        for (int q = 0; q < 36; ++q) {
            float4 e = ev[q];
            float4 v = xv[q];
            ax = fmaf(e.x, v.x, ax);
            ay = fmaf(e.y, v.y, ay);
            az = fmaf(e.z, v.z, az);
            aw = fmaf(e.w, v.w, aw);
        }
        out[((long)b * T_ + t) * OUT_ + j] = bcg[j] + ((ax + ay) + (az + aw));
        return;
    }

    __shared__ short xls[2 * WROWS * 8 + 8];   // 17168 B: lo-half @0, hi-half @H1OFF
    int t0 = blockIdx.x * TB;

    // stage x window: global fp32 (coalesced) -> bf16 -> LDS; zero outside [0,T)
    for (int idx = tid; idx < 2 * WROWS; idx += 256) {
        int h = idx >= WROWS;
        int row = h ? idx - WROWS : idx;
        int t = t0 - 18 + row;
        short8 v = short8{0, 0, 0, 0, 0, 0, 0, 0};
        if (t >= 0 && t < T_) {
            const float4* p = (const float4*)(x + ((long)b * T_ + t) * 16 + h * 8);
            v = cvt8(p[0], p[1]);
        }
        *(short8*)(xls + h * H1OFF + row * 8) = v;
    }

    int lane = tid & 63, w = tid >> 6;
    int t = lane & 15, q = lane >> 4;
    int h = q & 1, qh = q >> 1;

    // W A-frags: read once per wave (coalesced 1KB loads, L1-hot)
    const unsigned short* pk0 = w2pk + lane * 8;          // tbl0: j = 0..15
    const unsigned short* pk1 = w2pk + 5120 + lane * 8;   // tbl1: j = 16..31
    short8 W0[10], W1[10];
#pragma unroll
    for (int ks = 0; ks < 10; ++ks) {
        W0[ks] = *(const short8*)(pk0 + ks * 512);
        W1[ks] = *(const short8*)(pk1 + ks * 512);
    }

    __syncthreads();

    const short* ap = xls + h * H1OFF + (w * 128 + t + qh) * 8;

    float4v acc[8][2];
#pragma unroll
    for (int mt = 0; mt < 8; ++mt) {
        acc[mt][0] = float4v{0.f, 0.f, 0.f, 0.f};
        acc[mt][1] = float4v{0.f, 0.f, 0.f, 0.f};
    }

#pragma unroll
    for (int ks = 0; ks < 10; ++ks) {
#pragma unroll
        for (int mt = 0; mt < 8; ++mt) {
            short8 xf = *(const short8*)(ap + (mt * 16 + 2 * ks) * 8);
            acc[mt][0] = __builtin_amdgcn_mfma_f32_16x16x32_bf16(W0[ks], xf, acc[mt][0], 0, 0, 0);
            acc[mt][1] = __builtin_amdgcn_mfma_f32_16x16x32_bf16(W1[ks], xf, acc[mt][1], 0, 0, 0);
        }
    }

    // epilogue: C col = t, row = j = q*4+reg (+16 for tbl1) -> float4 stores
    long outb = (long)b * T_;
    float4 bc0 = *(const float4*)(bcg + q * 4);
    float4 bc1 = (q < 2) ? *(const float4*)(bcg + 16 + q * 4) : make_float4(0.f, 0.f, 0.f, 0.f);
    bool edge = (blockIdx.x == 0);
#pragma unroll
    for (int mt = 0; mt < 8; ++mt) {
        int t_out = t0 + w * 128 + mt * 16 + t;
        if (!edge || t_out >= 9) {        // t<9 owned by head
            float* o = out + (outb + t_out) * OUT_;
            float4 v0 = make_float4(acc[mt][0][0] + bc0.x, acc[mt][0][1] + bc0.y,
                                    acc[mt][0][2] + bc0.z, acc[mt][0][3] + bc0.w);
            *(float4*)(o + q * 4) = v0;
            if (q < 2) {
                float4 v1 = make_float4(acc[mt][1][0] + bc1.x, acc[mt][1][1] + bc1.y,
                                        acc[mt][1][2] + bc1.z, acc[mt][1][3] + bc1.w);
                *(float4*)(o + 16 + q * 4) = v1;
            }
        }
    }
}

extern "C" void kernel_launch(void* const* d_in, const int* in_sizes, int n_in,
                              void* d_out, int out_size, void* d_ws, size_t ws_size,
                              hipStream_t stream) {
    const float* x  = (const float*)d_in[0];
    const float* w1 = (const float*)d_in[1];
    const float* b1 = (const float*)d_in[2];
    const float* wf = (const float*)d_in[3];
    const float* bf = (const float*)d_in[4];
    float* out = (float*)d_out;
    unsigned short* w2pk = (unsigned short*)d_ws;
    float* bcg = (float*)((char*)d_ws + WS_BC_OFF);
    float* Eg  = (float*)((char*)d_ws + WS_E_OFF);
    float* w1t = (float*)((char*)d_ws + WS_W1T_OFF);

    hipLaunchKernelGGL(pre_kernel, dim3(120), dim3(256), 0, stream, w1, w1t, w2pk);
    hipLaunchKernelGGL(prep_kernel, dim3(606), dim3(256), 0, stream,
                       w1t, b1, wf, bf, w2pk, bcg, Eg);
    hipLaunchKernelGGL(main_kernel, dim3(17, B_), dim3(256), 0, stream,
                       x, w2pk, bcg, out, Eg);
}